// Round 1
// baseline (2143.888 us; speedup 1.0000x reference)
//
#include <hip/hip_runtime.h>
#include <math.h>

#define CC 64
#define HH 256
#define WW 256
#define GG 4
#define GC 16
#define HWp (HH*WW)
#define LOG2E 1.44269504088896340736f

// ---------------- ws layout (floats) ----------------
static constexpr size_t OFF_BN   = 0;                      // scale[64], shift[64]
static constexpr size_t OFF_H    = 256;                    // h buffer (reused per side): 2*64*256*256
static constexpr size_t OFF_Q    = OFF_H   + 8388608;
static constexpr size_t OFF_K    = OFF_Q   + 8388608;
static constexpr size_t OFF_MQ   = OFF_K   + 8388608;      // 512*64
static constexpr size_t OFF_MK   = OFF_MQ  + 32768;
static constexpr size_t OFF_RMAX = OFF_MK  + 32768;        // 512*256 each
static constexpr size_t OFF_RINV = OFF_RMAX + 131072;
static constexpr size_t OFF_CMAX = OFF_RINV + 131072;
static constexpr size_t OFF_CINV = OFF_CMAX + 131072;

__global__ void bn_prep(const float* __restrict__ g, const float* __restrict__ be,
                        const float* __restrict__ mn, const float* __restrict__ va,
                        float* __restrict__ bnss) {
    int c = threadIdx.x;
    if (c < CC) {
        float sc = g[c] / sqrtf(va[c] + 1e-5f);
        bnss[c] = sc;
        bnss[64 + c] = be[c] - mn[c] * sc;
    }
}

// Grouped 3x3 conv on BN(x), leaky-relu 0.1.  One block per (b,g,y).
__global__ __launch_bounds__(256) void conv1_k(const float* __restrict__ x,
        const float* __restrict__ w1, const float* __restrict__ b1,
        const float* __restrict__ bnss, float* __restrict__ hout) {
    __shared__ float xin[GC*3*260];
    __shared__ float wl[GC*GC*9];
    int blk = blockIdx.x;
    int y = blk & 255;
    int g = (blk >> 8) & 3;
    int b = blk >> 10;
    int t = threadIdx.x;
    for (int idx = t; idx < GC*GC*9; idx += 256) wl[idx] = w1[g*GC*GC*9 + idx];
    for (int idx = t; idx < GC*3*258; idx += 256) {
        int col = idx % 258;
        int r = idx / 258;
        int yy = r % 3, ic = r / 3;
        int gx = col - 1;
        int gy = y + yy - 1;
        int cg = g*GC + ic;
        float v = 0.f;
        if (gx >= 0 && gx < WW && gy >= 0 && gy < HH)
            v = x[(size_t)b*CC*HWp + (cg*HH + gy)*WW + gx] * bnss[cg] + bnss[64+cg];
        xin[(ic*3 + yy)*260 + col] = v;
    }
    __syncthreads();
    int x4 = t & 63;
    int oc4 = t >> 6;
    float acc[4][4];
    #pragma unroll
    for (int k = 0; k < 4; ++k) {
        float bb = b1[g*GC + oc4*4 + k];
        #pragma unroll
        for (int p = 0; p < 4; ++p) acc[k][p] = bb;
    }
    for (int ic = 0; ic < GC; ++ic) {
        #pragma unroll
        for (int yy = 0; yy < 3; ++yy) {
            float v[4][3];
            #pragma unroll
            for (int p = 0; p < 4; ++p) {
                int base = (ic*3+yy)*260 + x4 + 64*p;
                v[p][0] = xin[base]; v[p][1] = xin[base+1]; v[p][2] = xin[base+2];
            }
            #pragma unroll
            for (int k = 0; k < 4; ++k) {
                #pragma unroll
                for (int dx = 0; dx < 3; ++dx) {
                    float wv = wl[((oc4*4+k)*GC + ic)*9 + yy*3 + dx];
                    #pragma unroll
                    for (int p = 0; p < 4; ++p) acc[k][p] += wv * v[p][dx];
                }
            }
        }
    }
    #pragma unroll
    for (int k = 0; k < 4; ++k) {
        int oc = g*GC + oc4*4 + k;
        #pragma unroll
        for (int p = 0; p < 4; ++p) {
            float a = acc[k][p];
            a = a > 0.f ? a : 0.1f*a;
            hout[(size_t)b*CC*HWp + (oc*HH + y)*WW + x4 + 64*p] = a;
        }
    }
}

// Grouped 3x3 conv on h + bias + residual BN(x), then 1x1 conv -> qout (scaled).
// One block per (b,y,half).
__global__ __launch_bounds__(256) void conv2_1x1_k(const float* __restrict__ hbuf,
        const float* __restrict__ x, const float* __restrict__ w2, const float* __restrict__ b2,
        const float* __restrict__ wq, const float* __restrict__ bq,
        const float* __restrict__ bnss, float* __restrict__ qout, float scaleOut) {
    __shared__ float hin[CC*3*132];
    __shared__ float rl[CC*132];
    int blk = blockIdx.x;
    int hf = blk & 1;
    int y = (blk >> 1) & 255;
    int b = blk >> 9;
    int t = threadIdx.x;
    int x0 = hf * 128;
    for (int idx = t; idx < CC*3*130; idx += 256) {
        int col = idx % 130;
        int r = idx / 130;
        int yy = r % 3, ic = r / 3;
        int gx = x0 - 1 + col;
        int gy = y + yy - 1;
        float v = 0.f;
        if (gx >= 0 && gx < WW && gy >= 0 && gy < HH)
            v = hbuf[(size_t)b*CC*HWp + (ic*HH + gy)*WW + gx];
        hin[(ic*3+yy)*132 + col] = v;
    }
    __syncthreads();
    int x64 = t & 63;
    int g = __builtin_amdgcn_readfirstlane(t >> 6);   // wave-uniform output group
    float acc[GC][2];
    #pragma unroll
    for (int k = 0; k < GC; ++k) { float bb = b2[g*GC+k]; acc[k][0] = bb; acc[k][1] = bb; }
    for (int icl = 0; icl < GC; ++icl) {
        int ic = g*GC + icl;
        #pragma unroll
        for (int yy = 0; yy < 3; ++yy) {
            float v[2][3];
            #pragma unroll
            for (int p = 0; p < 2; ++p) {
                int base = (ic*3+yy)*132 + x64 + 64*p;
                v[p][0] = hin[base]; v[p][1] = hin[base+1]; v[p][2] = hin[base+2];
            }
            #pragma unroll
            for (int k = 0; k < GC; ++k) {
                #pragma unroll
                for (int dx = 0; dx < 3; ++dx) {
                    float wv = w2[((g*GC+k)*GC + icl)*9 + yy*3 + dx];
                    acc[k][0] += wv*v[0][dx];
                    acc[k][1] += wv*v[1][dx];
                }
            }
        }
    }
    #pragma unroll
    for (int k = 0; k < GC; ++k) {
        int c = g*GC + k;
        #pragma unroll
        for (int p = 0; p < 2; ++p) {
            int gx = x0 + x64 + 64*p;
            float xv = x[(size_t)b*CC*HWp + (c*HH + y)*WW + gx] * bnss[c] + bnss[64+c];
            rl[c*132 + x64 + 64*p] = acc[k][p] + xv;
        }
    }
    __syncthreads();
    float a2[GC][2];
    #pragma unroll
    for (int k = 0; k < GC; ++k) { a2[k][0] = 0.f; a2[k][1] = 0.f; }
    for (int c = 0; c < CC; ++c) {
        float r0 = rl[c*132 + x64];
        float r1 = rl[c*132 + x64 + 64];
        #pragma unroll
        for (int k = 0; k < GC; ++k) {
            float wv = wq[(g*GC + k)*CC + c];
            a2[k][0] += wv*r0; a2[k][1] += wv*r1;
        }
    }
    #pragma unroll
    for (int k = 0; k < GC; ++k) {
        int o = g*GC + k;
        #pragma unroll
        for (int p = 0; p < 2; ++p)
            qout[(size_t)b*CC*HWp + (o*HH + y)*WW + x0 + x64 + 64*p] = (a2[k][p] + bq[o]) * scaleOut;
    }
}

// Per-row stats: mean-center Q,K; online row/col softmax max+sum.  One block per n.
__global__ __launch_bounds__(256) void s1_stats(const float* __restrict__ Qb, const float* __restrict__ Kb,
        float* __restrict__ mq, float* __restrict__ mk,
        float* __restrict__ rmax, float* __restrict__ rinv,
        float* __restrict__ cmax, float* __restrict__ cinv) {
    __shared__ float lq[256*68];
    __shared__ float lk[256*68];
    __shared__ float red[256];
    __shared__ float mql[64], mkl[64];
    int n = blockIdx.x;
    int y = n & 255, b = n >> 8;
    int t = threadIdx.x;
    const float* Qp = Qb + (size_t)b*CC*HWp + y*WW;
    const float* Kp = Kb + (size_t)b*CC*HWp + y*WW;
    for (int idx = t; idx < 64*256; idx += 256) {
        int c = idx >> 8, j = idx & 255;
        lq[j*68 + c] = Qp[c*HWp + j];
        lk[j*68 + c] = Kp[c*HWp + j];
    }
    __syncthreads();
    int c = t >> 2, qq = t & 3;
    float sq = 0.f, sk = 0.f;
    for (int j = qq*64; j < qq*64+64; ++j) { sq += lq[j*68 + c]; sk += lk[j*68 + c]; }
    red[t] = sq;
    __syncthreads();
    if (t < 64) { float m = (red[t*4]+red[t*4+1]+red[t*4+2]+red[t*4+3])*(1.f/256.f); mql[t] = m; mq[n*64+t] = m; }
    __syncthreads();
    red[t] = sk;
    __syncthreads();
    if (t < 64) { float m = (red[t*4]+red[t*4+1]+red[t*4+2]+red[t*4+3])*(1.f/256.f); mkl[t] = m; mk[n*64+t] = m; }
    __syncthreads();
    for (int idx = t; idx < 64*256; idx += 256) {
        int c2 = idx & 63, j = idx >> 6;
        lq[j*68 + c2] -= mql[c2];
        lk[j*68 + c2] -= mkl[c2];
    }
    __syncthreads();
    {   // row stats: thread = i
        float4 q4[16];
        const float4* qr = (const float4*)(lq + t*68);
        #pragma unroll
        for (int c4 = 0; c4 < 16; ++c4) q4[c4] = qr[c4];
        float m = -3.0e38f, s = 0.f;
        for (int j = 0; j < 256; ++j) {
            const float4* kr = (const float4*)(lk + j*68);
            float e0=0,e1=0,e2=0,e3=0;
            #pragma unroll
            for (int c4 = 0; c4 < 16; ++c4) {
                float4 kv = kr[c4];
                e0 += q4[c4].x*kv.x; e1 += q4[c4].y*kv.y; e2 += q4[c4].z*kv.z; e3 += q4[c4].w*kv.w;
            }
            float E = (e0+e1)+(e2+e3);
            float m2 = fmaxf(m, E);
            s = s*exp2f(m - m2) + exp2f(E - m2);
            m = m2;
        }
        rmax[n*256+t] = m;
        rinv[n*256+t] = 1.f/s;
    }
    {   // col stats: thread = j
        float4 k4[16];
        const float4* kr = (const float4*)(lk + t*68);
        #pragma unroll
        for (int c4 = 0; c4 < 16; ++c4) k4[c4] = kr[c4];
        float m = -3.0e38f, s = 0.f;
        for (int i = 0; i < 256; ++i) {
            const float4* qr2 = (const float4*)(lq + i*68);
            float e0=0,e1=0,e2=0,e3=0;
            #pragma unroll
            for (int c4 = 0; c4 < 16; ++c4) {
                float4 qv = qr2[c4];
                e0 += k4[c4].x*qv.x; e1 += k4[c4].y*qv.y; e2 += k4[c4].z*qv.z; e3 += k4[c4].w*qv.w;
            }
            float E = (e0+e1)+(e2+e3);
            float m2 = fmaxf(m, E);
            s = s*exp2f(m - m2) + exp2f(E - m2);
            m = m2;
        }
        cmax[n*256+t] = m;
        cinv[n*256+t] = 1.f/s;
    }
}

// Apply (left): row layout, thread = i.  V_left + x_leftT + blend.  One block per n.
__global__ __launch_bounds__(256) void s2_left(const float* __restrict__ Qb, const float* __restrict__ Kb,
        const float* __restrict__ xl, const float* __restrict__ xr,
        const float* __restrict__ mq, const float* __restrict__ mk,
        const float* __restrict__ rmax, const float* __restrict__ rinv,
        const float* __restrict__ cmax, const float* __restrict__ cinv,
        float* __restrict__ outl) {
    __shared__ float lk[256*68];
    __shared__ float lxr[256*68];
    __shared__ float cmaxl[256], cinvl[256];
    __shared__ float la[8*264];
    __shared__ float mkl2[64];
    int n = blockIdx.x;
    int y = n & 255, b = n >> 8;
    int t = threadIdx.x;
    const float* Kp  = Kb + (size_t)b*CC*HWp + y*WW;
    const float* xrp = xr + (size_t)b*CC*HWp + y*WW;
    if (t < 64) mkl2[t] = mk[n*64+t];
    cmaxl[t] = cmax[n*256+t];
    cinvl[t] = cinv[n*256+t];
    if (t < 8) { la[t*264]=0.f; la[t*264+1]=0.f; la[t*264+258]=0.f; la[t*264+259]=0.f; }
    __syncthreads();
    for (int idx = t; idx < 64*256; idx += 256) {
        int c = idx >> 8, j = idx & 255;
        lk[j*68 + c]  = Kp[c*HWp + j] - mkl2[c];
        lxr[j*68 + c] = xrp[c*HWp + j];
    }
    float rmx = rmax[n*256+t];
    float rin = rinv[n*256+t];
    float4 q4[16];
    {
        const float* Qp = Qb + (size_t)b*CC*HWp + y*WW;
        #pragma unroll
        for (int c4 = 0; c4 < 16; ++c4) {
            float4 v;
            v.x = Qp[(c4*4+0)*HWp + t] - mq[n*64 + c4*4+0];
            v.y = Qp[(c4*4+1)*HWp + t] - mq[n*64 + c4*4+1];
            v.z = Qp[(c4*4+2)*HWp + t] - mq[n*64 + c4*4+2];
            v.w = Qp[(c4*4+3)*HWp + t] - mq[n*64 + c4*4+3];
            q4[c4] = v;
        }
    }
    __syncthreads();
    float4 acc[16];
    #pragma unroll
    for (int c4 = 0; c4 < 16; ++c4) acc[c4] = make_float4(0.f,0.f,0.f,0.f);
    float vl = 0.f;
    for (int tile = 0; tile < 32; ++tile) {
        float bsave[8];
        #pragma unroll
        for (int jj = 0; jj < 8; ++jj) {
            int j = tile*8 + jj;
            const float4* kr = (const float4*)(lk + j*68);
            float e0=0,e1=0,e2=0,e3=0;
            #pragma unroll
            for (int c4 = 0; c4 < 16; ++c4) {
                float4 kv = kr[c4];
                e0 += q4[c4].x*kv.x; e1 += q4[c4].y*kv.y; e2 += q4[c4].z*kv.z; e3 += q4[c4].w*kv.w;
            }
            float E = (e0+e1)+(e2+e3);
            float a = exp2f(E - rmx) * rin;
            bsave[jj] = exp2f(E - cmaxl[j]) * cinvl[j];
            la[jj*264 + 2 + t] = a;
            const float4* xr4 = (const float4*)(lxr + j*68);
            #pragma unroll
            for (int c4 = 0; c4 < 16; ++c4) {
                float4 xv = xr4[c4];
                acc[c4].x += a*xv.x; acc[c4].y += a*xv.y; acc[c4].z += a*xv.z; acc[c4].w += a*xv.w;
            }
        }
        __syncthreads();
        #pragma unroll
        for (int jj = 0; jj < 8; ++jj) {
            const float* ar = la + jj*264 + t;
            float at = ar[0]+ar[1]+ar[2]+ar[3]+ar[4];
            vl += bsave[jj]*at;
        }
        __syncthreads();
    }
    float vt = tanhf(5.f*vl);
    float om = 1.f - vt;
    const float* xlp = xl + (size_t)b*CC*HWp + y*WW;
    float* op = outl + (size_t)b*CC*HWp + y*WW;
    #pragma unroll
    for (int c4 = 0; c4 < 16; ++c4) {
        float xv;
        xv = xlp[(c4*4+0)*HWp + t]; op[(c4*4+0)*HWp + t] = xv*om + acc[c4].x*vt;
        xv = xlp[(c4*4+1)*HWp + t]; op[(c4*4+1)*HWp + t] = xv*om + acc[c4].y*vt;
        xv = xlp[(c4*4+2)*HWp + t]; op[(c4*4+2)*HWp + t] = xv*om + acc[c4].z*vt;
        xv = xlp[(c4*4+3)*HWp + t]; op[(c4*4+3)*HWp + t] = xv*om + acc[c4].w*vt;
    }
}

// Apply (right): column layout, thread = j.  V_right + x_rightT + blend.  One block per n.
__global__ __launch_bounds__(256) void s3_right(const float* __restrict__ Qb, const float* __restrict__ Kb,
        const float* __restrict__ xl, const float* __restrict__ xr,
        const float* __restrict__ mq, const float* __restrict__ mk,
        const float* __restrict__ rmax, const float* __restrict__ rinv,
        const float* __restrict__ cmax, const float* __restrict__ cinv,
        float* __restrict__ outr) {
    __shared__ float lq[256*68];
    __shared__ float lxl[256*68];
    __shared__ float rmaxl[256], rinvl[256];
    __shared__ float lb[8*264];
    __shared__ float mql2[64];
    int n = blockIdx.x;
    int y = n & 255, b = n >> 8;
    int t = threadIdx.x;
    const float* Qp  = Qb + (size_t)b*CC*HWp + y*WW;
    const float* xlp = xl + (size_t)b*CC*HWp + y*WW;
    if (t < 64) mql2[t] = mq[n*64+t];
    rmaxl[t] = rmax[n*256+t];
    rinvl[t] = rinv[n*256+t];
    if (t < 8) { lb[t*264]=0.f; lb[t*264+1]=0.f; lb[t*264+258]=0.f; lb[t*264+259]=0.f; }
    __syncthreads();
    for (int idx = t; idx < 64*256; idx += 256) {
        int c = idx >> 8, i = idx & 255;
        lq[i*68 + c]  = Qp[c*HWp + i] - mql2[c];
        lxl[i*68 + c] = xlp[c*HWp + i];
    }
    float cmx = cmax[n*256+t];
    float cin = cinv[n*256+t];
    float4 k4[16];
    {
        const float* Kp = Kb + (size_t)b*CC*HWp + y*WW;
        #pragma unroll
        for (int c4 = 0; c4 < 16; ++c4) {
            float4 v;
            v.x = Kp[(c4*4+0)*HWp + t] - mk[n*64 + c4*4+0];
            v.y = Kp[(c4*4+1)*HWp + t] - mk[n*64 + c4*4+1];
            v.z = Kp[(c4*4+2)*HWp + t] - mk[n*64 + c4*4+2];
            v.w = Kp[(c4*4+3)*HWp + t] - mk[n*64 + c4*4+3];
            k4[c4] = v;
        }
    }
    __syncthreads();
    float4 acc[16];
    #pragma unroll
    for (int c4 = 0; c4 < 16; ++c4) acc[c4] = make_float4(0.f,0.f,0.f,0.f);
    float vr = 0.f;
    for (int tile = 0; tile < 32; ++tile) {
        float asave[8];
        #pragma unroll
        for (int ii = 0; ii < 8; ++ii) {
            int i = tile*8 + ii;
            const float4* qr = (const float4*)(lq + i*68);
            float e0=0,e1=0,e2=0,e3=0;
            #pragma unroll
            for (int c4 = 0; c4 < 16; ++c4) {
                float4 qv = qr[c4];
                e0 += k4[c4].x*qv.x; e1 += k4[c4].y*qv.y; e2 += k4[c4].z*qv.z; e3 += k4[c4].w*qv.w;
            }
            float E = (e0+e1)+(e2+e3);
            asave[ii] = exp2f(E - rmaxl[i]) * rinvl[i];
            float bb = exp2f(E - cmx) * cin;
            lb[ii*264 + 2 + t] = bb;
            const float4* xl4 = (const float4*)(lxl + i*68);
            #pragma unroll
            for (int c4 = 0; c4 < 16; ++c4) {
                float4 xv = xl4[c4];
                acc[c4].x += bb*xv.x; acc[c4].y += bb*xv.y; acc[c4].z += bb*xv.z; acc[c4].w += bb*xv.w;
            }
        }
        __syncthreads();
        #pragma unroll
        for (int ii = 0; ii < 8; ++ii) {
            const float* br = lb + ii*264 + t;
            float bt = br[0]+br[1]+br[2]+br[3]+br[4];
            vr += asave[ii]*bt;
        }
        __syncthreads();
    }
    float vt = tanhf(5.f*vr);
    float om = 1.f - vt;
    const float* xrp = xr + (size_t)b*CC*HWp + y*WW;
    float* op = outr + (size_t)b*CC*HWp + y*WW;
    #pragma unroll
    for (int c4 = 0; c4 < 16; ++c4) {
        float xv;
        xv = xrp[(c4*4+0)*HWp + t]; op[(c4*4+0)*HWp + t] = xv*om + acc[c4].x*vt;
        xv = xrp[(c4*4+1)*HWp + t]; op[(c4*4+1)*HWp + t] = xv*om + acc[c4].y*vt;
        xv = xrp[(c4*4+2)*HWp + t]; op[(c4*4+2)*HWp + t] = xv*om + acc[c4].z*vt;
        xv = xrp[(c4*4+3)*HWp + t]; op[(c4*4+3)*HWp + t] = xv*om + acc[c4].w*vt;
    }
}

extern "C" void kernel_launch(void* const* d_in, const int* in_sizes, int n_in,
                              void* d_out, int out_size, void* d_ws, size_t ws_size,
                              hipStream_t stream) {
    const float* x_left  = (const float*)d_in[0];
    const float* x_right = (const float*)d_in[1];
    const float* bn_g = (const float*)d_in[4];
    const float* bn_b = (const float*)d_in[5];
    const float* bn_m = (const float*)d_in[6];
    const float* bn_v = (const float*)d_in[7];
    const float* w1  = (const float*)d_in[8];
    const float* b1  = (const float*)d_in[9];
    const float* w2  = (const float*)d_in[10];
    const float* b2  = (const float*)d_in[11];
    const float* bqw = (const float*)d_in[12];
    const float* bqb = (const float*)d_in[13];
    const float* bsw = (const float*)d_in[14];
    const float* bsb = (const float*)d_in[15];

    float* ws   = (float*)d_ws;
    float* bnss = ws + OFF_BN;
    float* hbuf = ws + OFF_H;
    float* Qb   = ws + OFF_Q;
    float* Kb   = ws + OFF_K;
    float* mqp  = ws + OFF_MQ;
    float* mkp  = ws + OFF_MK;
    float* rmaxp = ws + OFF_RMAX;
    float* rinvp = ws + OFF_RINV;
    float* cmaxp = ws + OFF_CMAX;
    float* cinvp = ws + OFF_CINV;

    float* outl = (float*)d_out;
    float* outr = outl + (size_t)2*CC*HWp;

    hipLaunchKernelGGL(bn_prep, dim3(1), dim3(64), 0, stream, bn_g, bn_b, bn_m, bn_v, bnss);
    // left path -> Q (scaled by log2 e)
    hipLaunchKernelGGL(conv1_k, dim3(2048), dim3(256), 0, stream, x_left, w1, b1, bnss, hbuf);
    hipLaunchKernelGGL(conv2_1x1_k, dim3(1024), dim3(256), 0, stream, hbuf, x_left, w2, b2, bqw, bqb, bnss, Qb, LOG2E);
    // right path -> K
    hipLaunchKernelGGL(conv1_k, dim3(2048), dim3(256), 0, stream, x_right, w1, b1, bnss, hbuf);
    hipLaunchKernelGGL(conv2_1x1_k, dim3(1024), dim3(256), 0, stream, hbuf, x_right, w2, b2, bsw, bsb, bnss, Kb, 1.0f);
    // attention rows
    hipLaunchKernelGGL(s1_stats, dim3(512), dim3(256), 0, stream, Qb, Kb, mqp, mkp, rmaxp, rinvp, cmaxp, cinvp);
    hipLaunchKernelGGL(s2_left,  dim3(512), dim3(256), 0, stream, Qb, Kb, x_left, x_right, mqp, mkp, rmaxp, rinvp, cmaxp, cinvp, outl);
    hipLaunchKernelGGL(s3_right, dim3(512), dim3(256), 0, stream, Qb, Kb, x_left, x_right, mqp, mkp, rmaxp, rinvp, cmaxp, cinvp, outr);
}

// Round 2
// 1033.883 us; speedup vs baseline: 2.0736x; 2.0736x over previous
//
#include <hip/hip_runtime.h>
#include <math.h>

#define CC 64
#define HH 256
#define WW 256
#define GG 4
#define GC 16
#define HWp (HH*WW)
#define LOG2E 1.44269504088896340736f
#define NB 512

typedef __attribute__((ext_vector_type(8))) short short8;
typedef __attribute__((ext_vector_type(4))) float f32x4;
typedef __attribute__((ext_vector_type(4))) unsigned short u16x4;

static constexpr size_t OFF_BN   = 0;
static constexpr size_t OFF_H    = 256;                 // 8.39M floats; later aliased by Qhi/Qlo (bf16)
static constexpr size_t OFF_QF   = OFF_H  + 8388608;    // Q f32 [n][i][c]; later aliased by Khi/Klo
static constexpr size_t OFF_KF   = OFF_QF + 8388608;    // K f32 [n][i][c]
static constexpr size_t OFF_RMAX = OFF_KF + 8388608;
static constexpr size_t OFF_RINV = OFF_RMAX + 131072;
static constexpr size_t OFF_CMAX = OFF_RINV + 131072;
static constexpr size_t OFF_CINV = OFF_CMAX + 131072;

__device__ __forceinline__ unsigned short f2bf(float v) {
    unsigned int u = __float_as_uint(v);
    return (unsigned short)((u + 0x7fffu + ((u >> 16) & 1u)) >> 16);
}
__device__ __forceinline__ float bf2f(unsigned short h) {
    return __uint_as_float(((unsigned int)h) << 16);
}

__global__ void bn_prep(const float* __restrict__ g, const float* __restrict__ be,
                        const float* __restrict__ mn, const float* __restrict__ va,
                        float* __restrict__ bnss) {
    int c = threadIdx.x;
    if (c < CC) {
        float sc = g[c] / sqrtf(va[c] + 1e-5f);
        bnss[c] = sc;
        bnss[64 + c] = be[c] - mn[c] * sc;
    }
}

// Grouped 3x3 conv on BN(x), leaky-relu 0.1.  One block per (b,g,y).
__global__ __launch_bounds__(256) void conv1_k(const float* __restrict__ x,
        const float* __restrict__ w1, const float* __restrict__ b1,
        const float* __restrict__ bnss, float* __restrict__ hout) {
    __shared__ float xin[GC*3*260];
    __shared__ float wl[GC*GC*9];
    int blk = blockIdx.x;
    int y = blk & 255;
    int g = (blk >> 8) & 3;
    int b = blk >> 10;
    int t = threadIdx.x;
    for (int idx = t; idx < GC*GC*9; idx += 256) wl[idx] = w1[g*GC*GC*9 + idx];
    for (int idx = t; idx < GC*3*258; idx += 256) {
        int col = idx % 258;
        int r = idx / 258;
        int yy = r % 3, ic = r / 3;
        int gx = col - 1;
        int gy = y + yy - 1;
        int cg = g*GC + ic;
        float v = 0.f;
        if (gx >= 0 && gx < WW && gy >= 0 && gy < HH)
            v = x[(size_t)b*CC*HWp + (cg*HH + gy)*WW + gx] * bnss[cg] + bnss[64+cg];
        xin[(ic*3 + yy)*260 + col] = v;
    }
    __syncthreads();
    int x4 = t & 63;
    int oc4 = t >> 6;
    float acc[4][4];
    #pragma unroll
    for (int k = 0; k < 4; ++k) {
        float bb = b1[g*GC + oc4*4 + k];
        #pragma unroll
        for (int p = 0; p < 4; ++p) acc[k][p] = bb;
    }
    for (int ic = 0; ic < GC; ++ic) {
        #pragma unroll
        for (int yy = 0; yy < 3; ++yy) {
            float v[4][3];
            #pragma unroll
            for (int p = 0; p < 4; ++p) {
                int base = (ic*3+yy)*260 + x4 + 64*p;
                v[p][0] = xin[base]; v[p][1] = xin[base+1]; v[p][2] = xin[base+2];
            }
            #pragma unroll
            for (int k = 0; k < 4; ++k) {
                #pragma unroll
                for (int dx = 0; dx < 3; ++dx) {
                    float wv = wl[((oc4*4+k)*GC + ic)*9 + yy*3 + dx];
                    #pragma unroll
                    for (int p = 0; p < 4; ++p) acc[k][p] += wv * v[p][dx];
                }
            }
        }
    }
    #pragma unroll
    for (int k = 0; k < 4; ++k) {
        int oc = g*GC + oc4*4 + k;
        #pragma unroll
        for (int p = 0; p < 4; ++p) {
            float a = acc[k][p];
            a = a > 0.f ? a : 0.1f*a;
            hout[(size_t)b*CC*HWp + (oc*HH + y)*WW + x4 + 64*p] = a;
        }
    }
}

// Grouped 3x3 conv on h + bias + residual BN(x), then 1x1 conv -> qf32 [n][i][c].
// One block per (b,y,half).
__global__ __launch_bounds__(256) void conv2_k(const float* __restrict__ hbuf,
        const float* __restrict__ x, const float* __restrict__ w2, const float* __restrict__ b2,
        const float* __restrict__ wq, const float* __restrict__ bq,
        const float* __restrict__ bnss, float* __restrict__ qf32) {
    __shared__ float hin[CC*3*132];
    __shared__ float rl[CC*132];
    int blk = blockIdx.x;
    int hf = blk & 1;
    int y = (blk >> 1) & 255;
    int b = blk >> 9;
    int t = threadIdx.x;
    int x0 = hf * 128;
    for (int idx = t; idx < CC*3*130; idx += 256) {
        int col = idx % 130;
        int r = idx / 130;
        int yy = r % 3, ic = r / 3;
        int gx = x0 - 1 + col;
        int gy = y + yy - 1;
        float v = 0.f;
        if (gx >= 0 && gx < WW && gy >= 0 && gy < HH)
            v = hbuf[(size_t)b*CC*HWp + (ic*HH + gy)*WW + gx];
        hin[(ic*3+yy)*132 + col] = v;
    }
    __syncthreads();
    int x64 = t & 63;
    int g = __builtin_amdgcn_readfirstlane(t >> 6);
    float acc[GC][2];
    #pragma unroll
    for (int k = 0; k < GC; ++k) { float bb = b2[g*GC+k]; acc[k][0] = bb; acc[k][1] = bb; }
    for (int icl = 0; icl < GC; ++icl) {
        int ic = g*GC + icl;
        #pragma unroll
        for (int yy = 0; yy < 3; ++yy) {
            float v[2][3];
            #pragma unroll
            for (int p = 0; p < 2; ++p) {
                int base = (ic*3+yy)*132 + x64 + 64*p;
                v[p][0] = hin[base]; v[p][1] = hin[base+1]; v[p][2] = hin[base+2];
            }
            #pragma unroll
            for (int k = 0; k < GC; ++k) {
                #pragma unroll
                for (int dx = 0; dx < 3; ++dx) {
                    float wv = w2[((g*GC+k)*GC + icl)*9 + yy*3 + dx];
                    acc[k][0] += wv*v[0][dx];
                    acc[k][1] += wv*v[1][dx];
                }
            }
        }
    }
    #pragma unroll
    for (int k = 0; k < GC; ++k) {
        int c = g*GC + k;
        #pragma unroll
        for (int p = 0; p < 2; ++p) {
            int gx = x0 + x64 + 64*p;
            float xv = x[(size_t)b*CC*HWp + (c*HH + y)*WW + gx] * bnss[c] + bnss[64+c];
            rl[c*132 + x64 + 64*p] = acc[k][p] + xv;
        }
    }
    __syncthreads();
    float a2[GC][2];
    #pragma unroll
    for (int k = 0; k < GC; ++k) { a2[k][0] = 0.f; a2[k][1] = 0.f; }
    for (int c = 0; c < CC; ++c) {
        float r0 = rl[c*132 + x64];
        float r1 = rl[c*132 + x64 + 64];
        #pragma unroll
        for (int k = 0; k < GC; ++k) {
            float wv = wq[(g*GC + k)*CC + c];
            a2[k][0] += wv*r0; a2[k][1] += wv*r1;
        }
    }
    // transpose via LDS (reuse hin) and write [n][i][c] coalesced
    float* lds_t = hin;   // need 128*68 floats = 34816B <= hin
    __syncthreads();
    #pragma unroll
    for (int k = 0; k < GC; ++k) {
        int o = g*GC + k;
        float bb = bq[o];
        lds_t[(x64      )*68 + o] = a2[k][0] + bb;
        lds_t[(x64 + 64 )*68 + o] = a2[k][1] + bb;
    }
    __syncthreads();
    int iL = t >> 1, ch = (t & 1) * 32;
    size_t gb = ((size_t)(b*256 + y)*256 + (size_t)(x0 + iL))*64 + ch;
    #pragma unroll
    for (int u = 0; u < 8; ++u) {
        float4 vv = *(float4*)&lds_t[iL*68 + ch + u*4];
        *(float4*)&qf32[gb + u*4] = vv;
    }
}

// mean-center over i (width), scale, split to bf16 hi/lo.  One block per n.
__global__ __launch_bounds__(256) void csplit(const float* __restrict__ src,
        unsigned short* __restrict__ hi, unsigned short* __restrict__ lo, float scale) {
    __shared__ float ld[256*68];
    __shared__ float mean[64];
    int n = blockIdx.x, t = threadIdx.x;
    const float* sp = src + (size_t)n*16384;
    for (int idx = t; idx < 16384; idx += 256) {
        int i = idx >> 6, c = idx & 63;
        ld[i*68 + c] = sp[idx];
    }
    __syncthreads();
    if (t < 64) {
        float s = 0.f;
        for (int i = 0; i < 256; ++i) s += ld[i*68 + t];
        mean[t] = s * (1.f/256.f);
    }
    __syncthreads();
    size_t ob = (size_t)n*16384 + (size_t)t*64;
    #pragma unroll
    for (int c4 = 0; c4 < 16; ++c4) {
        float4 v = *(float4*)&ld[t*68 + c4*4];
        u16x4 vh, vl;
        #pragma unroll
        for (int e = 0; e < 4; ++e) {
            float f = ((&v.x)[e] - mean[c4*4+e]) * scale;
            unsigned short h = f2bf(f);
            vh[e] = h;
            vl[e] = f2bf(f - bf2f(h));
        }
        *(u16x4*)(hi + ob + c4*4) = vh;
        *(u16x4*)(lo + ob + c4*4) = vl;
    }
}

// ---- MFMA attention.  E computed as 16x16x32 bf16 with hi/lo split. ----
// A-frag: row = l&15, k = (l>>4)*8 + e (contiguous 8 bf16).  B-frag symmetric.
// C/D:    col = l&15, row = (l>>4)*4 + reg.

__global__ __launch_bounds__(256) void s1_stats(
        const unsigned short* __restrict__ Qhi, const unsigned short* __restrict__ Qlo,
        const unsigned short* __restrict__ Khi, const unsigned short* __restrict__ Klo,
        float* __restrict__ rmax, float* __restrict__ rinv,
        float* __restrict__ cmax, float* __restrict__ cinv) {
    __shared__ float colred[4][256][2];
    int n = blockIdx.x;
    int t = threadIdx.x;
    int w = t >> 6, l = t & 63;
    int lr = l & 15, lg = l >> 4;
    const size_t qb = (size_t)n * 16384;

    short8 qh[4][2], ql[4][2];
    #pragma unroll
    for (int rf = 0; rf < 4; ++rf)
        #pragma unroll
        for (int ks = 0; ks < 2; ++ks) {
            size_t a = qb + (size_t)(w*64 + rf*16 + lr)*64 + ks*32 + lg*8;
            qh[rf][ks] = *reinterpret_cast<const short8*>(Qhi + a);
            ql[rf][ks] = *reinterpret_cast<const short8*>(Qlo + a);
        }

    float mrow[4][4], srow[4][4];
    #pragma unroll
    for (int rf = 0; rf < 4; ++rf)
        #pragma unroll
        for (int r = 0; r < 4; ++r) { mrow[rf][r] = -3.0e38f; srow[rf][r] = 0.f; }

    for (int jt = 0; jt < 8; ++jt) {
        short8 kh[2][2], kl[2][2];
        #pragma unroll
        for (int cf = 0; cf < 2; ++cf)
            #pragma unroll
            for (int ks = 0; ks < 2; ++ks) {
                size_t a = qb + (size_t)(jt*32 + cf*16 + lr)*64 + ks*32 + lg*8;
                kh[cf][ks] = *reinterpret_cast<const short8*>(Khi + a);
                kl[cf][ks] = *reinterpret_cast<const short8*>(Klo + a);
            }
        f32x4 acc[4][2];
        #pragma unroll
        for (int rf = 0; rf < 4; ++rf)
            #pragma unroll
            for (int cf = 0; cf < 2; ++cf) acc[rf][cf] = (f32x4){0.f,0.f,0.f,0.f};
        #pragma unroll
        for (int ks = 0; ks < 2; ++ks)
            #pragma unroll
            for (int rf = 0; rf < 4; ++rf)
                #pragma unroll
                for (int cf = 0; cf < 2; ++cf) {
                    acc[rf][cf] = __builtin_amdgcn_mfma_f32_16x16x32_bf16(qh[rf][ks], kh[cf][ks], acc[rf][cf], 0,0,0);
                    acc[rf][cf] = __builtin_amdgcn_mfma_f32_16x16x32_bf16(qh[rf][ks], kl[cf][ks], acc[rf][cf], 0,0,0);
                    acc[rf][cf] = __builtin_amdgcn_mfma_f32_16x16x32_bf16(ql[rf][ks], kh[cf][ks], acc[rf][cf], 0,0,0);
                }
        // row online update
        #pragma unroll
        for (int rf = 0; rf < 4; ++rf)
            #pragma unroll
            for (int r = 0; r < 4; ++r) {
                float e0 = acc[rf][0][r], e1 = acc[rf][1][r];
                float m2 = fmaxf(mrow[rf][r], fmaxf(e0, e1));
                srow[rf][r] = srow[rf][r]*exp2f(mrow[rf][r]-m2) + exp2f(e0-m2) + exp2f(e1-m2);
                mrow[rf][r] = m2;
            }
        // col stats for this jtile (per cf), merge across lg groups, write LDS
        #pragma unroll
        for (int cf = 0; cf < 2; ++cf) {
            float m = acc[0][cf][0];
            #pragma unroll
            for (int rf = 0; rf < 4; ++rf)
                #pragma unroll
                for (int r = 0; r < 4; ++r) m = fmaxf(m, acc[rf][cf][r]);
            float s = 0.f;
            #pragma unroll
            for (int rf = 0; rf < 4; ++rf)
                #pragma unroll
                for (int r = 0; r < 4; ++r) s += exp2f(acc[rf][cf][r] - m);
            #pragma unroll
            for (int mask = 16; mask <= 32; mask <<= 1) {
                float om = __shfl_xor(m, mask);
                float os = __shfl_xor(s, mask);
                float m2 = fmaxf(m, om);
                s = s*exp2f(m-m2) + os*exp2f(om-m2);
                m = m2;
            }
            if (lg == 0) {
                int j = jt*32 + cf*16 + lr;
                colred[w][j][0] = m;
                colred[w][j][1] = s;
            }
        }
    }
    // row reduce across the 16 col-lanes
    #pragma unroll
    for (int rf = 0; rf < 4; ++rf)
        #pragma unroll
        for (int r = 0; r < 4; ++r) {
            float m = mrow[rf][r], s = srow[rf][r];
            #pragma unroll
            for (int mask = 1; mask <= 8; mask <<= 1) {
                float om = __shfl_xor(m, mask);
                float os = __shfl_xor(s, mask);
                float m2 = fmaxf(m, om);
                s = s*exp2f(m-m2) + os*exp2f(om-m2);
                m = m2;
            }
            if (lr == 0) {
                int row = w*64 + rf*16 + lg*4 + r;
                rmax[n*256 + row] = m;
                rinv[n*256 + row] = 1.f / s;
            }
        }
    __syncthreads();
    {
        int j = t;
        float m = colred[0][j][0], s = colred[0][j][1];
        #pragma unroll
        for (int w2_ = 1; w2_ < 4; ++w2_) {
            float om = colred[w2_][j][0], os = colred[w2_][j][1];
            float m2 = fmaxf(m, om);
            s = s*exp2f(m-m2) + os*exp2f(om-m2);
            m = m2;
        }
        cmax[n*256 + j] = m;
        cinv[n*256 + j] = 1.f / s;
    }
}

// Symmetric apply kernel.  rows = "a" frame (row-softmax side), cols = "b" frame.
// s2_left : A=Q, B=K, rowstats=(rmax,rinv), colstats=(cmax,cinv), Xpv=x_right, Xblend=x_left -> out_left
// s3_right: A=K, B=Q, rowstats=(cmax,cinv), colstats=(rmax,rinv), Xpv=x_left,  Xblend=x_right -> out_right
__global__ __launch_bounds__(256) void s23_apply(
        const unsigned short* __restrict__ Ahi, const unsigned short* __restrict__ Alo,
        const unsigned short* __restrict__ Bhi, const unsigned short* __restrict__ Blo,
        const float* __restrict__ rowmax, const float* __restrict__ rowinv,
        const float* __restrict__ colmax, const float* __restrict__ colinv,
        const float* __restrict__ Xpv, const float* __restrict__ Xblend,
        float* __restrict__ outp) {
    __shared__ unsigned short pa[256][40];
    __shared__ unsigned short pb[256][40];
    __shared__ float vred[4][256];
    __shared__ float cmax_l[256], cinv_l[256];
    __shared__ float vfin[256];
    int n = blockIdx.x;
    int y = n & 255, b = n >> 8;
    int t = threadIdx.x;
    int w = t >> 6, l = t & 63;
    int lr = l & 15, lg = l >> 4;
    const size_t qb = (size_t)n * 16384;

    cmax_l[t] = colmax[n*256 + t];
    cinv_l[t] = colinv[n*256 + t];
    for (int q = t; q < 1024; q += 256) ((float*)vred)[q] = 0.f;

    float rmx[4][4], rin[4][4];
    #pragma unroll
    for (int rf = 0; rf < 4; ++rf)
        #pragma unroll
        for (int r = 0; r < 4; ++r) {
            int row = w*64 + rf*16 + lg*4 + r;
            rmx[rf][r] = rowmax[n*256 + row];
            rin[rf][r] = rowinv[n*256 + row];
        }

    short8 ah[4][2], al[4][2];
    #pragma unroll
    for (int rf = 0; rf < 4; ++rf)
        #pragma unroll
        for (int ks = 0; ks < 2; ++ks) {
            size_t a = qb + (size_t)(w*64 + rf*16 + lr)*64 + ks*32 + lg*8;
            ah[rf][ks] = *reinterpret_cast<const short8*>(Ahi + a);
            al[rf][ks] = *reinterpret_cast<const short8*>(Alo + a);
        }

    f32x4 pv[4][4];
    #pragma unroll
    for (int rf = 0; rf < 4; ++rf)
        #pragma unroll
        for (int cf = 0; cf < 4; ++cf) pv[rf][cf] = (f32x4){0.f,0.f,0.f,0.f};
    float vacc[6];
    #pragma unroll
    for (int s = 0; s < 6; ++s) vacc[s] = 0.f;

    const float* xpvb = Xpv + (size_t)b*CC*HWp + (size_t)y*WW;
    __syncthreads();

    for (int jt = 0; jt < 8; ++jt) {
        short8 bh[2][2], bl[2][2];
        #pragma unroll
        for (int cf = 0; cf < 2; ++cf)
            #pragma unroll
            for (int ks = 0; ks < 2; ++ks) {
                size_t a = qb + (size_t)(jt*32 + cf*16 + lr)*64 + ks*32 + lg*8;
                bh[cf][ks] = *reinterpret_cast<const short8*>(Bhi + a);
                bl[cf][ks] = *reinterpret_cast<const short8*>(Blo + a);
            }
        f32x4 acc[4][2];
        #pragma unroll
        for (int rf = 0; rf < 4; ++rf)
            #pragma unroll
            for (int cf = 0; cf < 2; ++cf) acc[rf][cf] = (f32x4){0.f,0.f,0.f,0.f};
        #pragma unroll
        for (int ks = 0; ks < 2; ++ks)
            #pragma unroll
            for (int rf = 0; rf < 4; ++rf)
                #pragma unroll
                for (int cf = 0; cf < 2; ++cf) {
                    acc[rf][cf] = __builtin_amdgcn_mfma_f32_16x16x32_bf16(ah[rf][ks], bh[cf][ks], acc[rf][cf], 0,0,0);
                    acc[rf][cf] = __builtin_amdgcn_mfma_f32_16x16x32_bf16(ah[rf][ks], bl[cf][ks], acc[rf][cf], 0,0,0);
                    acc[rf][cf] = __builtin_amdgcn_mfma_f32_16x16x32_bf16(al[rf][ks], bh[cf][ks], acc[rf][cf], 0,0,0);
                }
        // a, b tiles -> LDS (bf16)
        #pragma unroll
        for (int rf = 0; rf < 4; ++rf)
            #pragma unroll
            for (int cf = 0; cf < 2; ++cf) {
                int col = cf*16 + lr;
                float cm = cmax_l[jt*32 + col];
                float ci = cinv_l[jt*32 + col];
                #pragma unroll
                for (int r = 0; r < 4; ++r) {
                    float e = acc[rf][cf][r];
                    int row = w*64 + rf*16 + lg*4 + r;
                    pa[row][col] = f2bf(exp2f(e - rmx[rf][r]) * rin[rf][r]);
                    pb[row][col] = f2bf(exp2f(e - cm) * ci);
                }
            }
        __syncthreads();
        // banded W = a @ b^T for the relaxed-V term
        #pragma unroll
        for (int Tl = 0; Tl < 4; ++Tl) {
            int T = w*4 + Tl;
            short8 afr = *reinterpret_cast<short8*>(&pa[T*16 + lr][lg*8]);
            #pragma unroll
            for (int dT = -1; dT <= 1; ++dT) {
                int Tp = T + dT;
                if (Tp < 0 || Tp > 15) continue;
                short8 bfr = *reinterpret_cast<short8*>(&pb[Tp*16 + lr][lg*8]);
                f32x4 wacc = (f32x4){0.f,0.f,0.f,0.f};
                wacc = __builtin_amdgcn_mfma_f32_16x16x32_bf16(afr, bfr, wacc, 0,0,0);
                #pragma unroll
                for (int r = 0; r < 4; ++r) {
                    int diff = lg*4 + r - lr - 16*dT;
                    if (diff >= -2 && diff <= 2) vacc[Tl + dT + 1] += wacc[r];
                }
            }
        }
        // PV: OL += a @ Xpv   (B-frag converted from f32 global on the fly)
        #pragma unroll
        for (int cf4 = 0; cf4 < 4; ++cf4) {
            const float* xp = xpvb + (size_t)(cf4*16 + lr)*HWp + jt*32 + lg*8;
            float4 xv0 = *(const float4*)(xp);
            float4 xv1 = *(const float4*)(xp + 4);
            short8 xf;
            xf[0] = (short)f2bf(xv0.x); xf[1] = (short)f2bf(xv0.y);
            xf[2] = (short)f2bf(xv0.z); xf[3] = (short)f2bf(xv0.w);
            xf[4] = (short)f2bf(xv1.x); xf[5] = (short)f2bf(xv1.y);
            xf[6] = (short)f2bf(xv1.z); xf[7] = (short)f2bf(xv1.w);
            #pragma unroll
            for (int rf = 0; rf < 4; ++rf) {
                short8 paf = *reinterpret_cast<short8*>(&pa[w*64 + rf*16 + lr][lg*8]);
                pv[rf][cf4] = __builtin_amdgcn_mfma_f32_16x16x32_bf16(paf, xf, pv[rf][cf4], 0,0,0);
            }
        }
        __syncthreads();
    }
    // V reduce
    #pragma unroll
    for (int s = 0; s < 6; ++s) {
        float v = vacc[s];
        v += __shfl_xor(v, 16);
        v += __shfl_xor(v, 32);
        if (lg == 0) {
            int i = (w*4 - 1 + s)*16 + lr;
            if (i >= 0 && i < 256) vred[w][i] = v;
        }
    }
    __syncthreads();
    vfin[t] = tanhf(5.f * (vred[0][t] + vred[1][t] + vred[2][t] + vred[3][t]));
    __syncthreads();
    // blend + write out (per-lane scattered 4B; L2 write-combines)
    const float* xbb = Xblend + (size_t)b*CC*HWp + (size_t)y*WW;
    float* ob = outp + (size_t)b*CC*HWp + (size_t)y*WW;
    #pragma unroll
    for (int rf = 0; rf < 4; ++rf)
        #pragma unroll
        for (int r = 0; r < 4; ++r) {
            int row = w*64 + rf*16 + lg*4 + r;
            float vt = vfin[row];
            #pragma unroll
            for (int cf4 = 0; cf4 < 4; ++cf4) {
                int c = cf4*16 + lr;
                size_t ga = (size_t)c*HWp + row;
                float xv = xbb[ga];
                ob[ga] = xv + vt * (pv[rf][cf4][r] - xv);
            }
        }
}

extern "C" void kernel_launch(void* const* d_in, const int* in_sizes, int n_in,
                              void* d_out, int out_size, void* d_ws, size_t ws_size,
                              hipStream_t stream) {
    const float* x_left  = (const float*)d_in[0];
    const float* x_right = (const float*)d_in[1];
    const float* bn_g = (const float*)d_in[4];
    const float* bn_b = (const float*)d_in[5];
    const float* bn_m = (const float*)d_in[6];
    const float* bn_v = (const float*)d_in[7];
    const float* w1  = (const float*)d_in[8];
    const float* b1  = (const float*)d_in[9];
    const float* w2  = (const float*)d_in[10];
    const float* b2  = (const float*)d_in[11];
    const float* bqw = (const float*)d_in[12];
    const float* bqb = (const float*)d_in[13];
    const float* bsw = (const float*)d_in[14];
    const float* bsb = (const float*)d_in[15];

    float* ws   = (float*)d_ws;
    float* bnss = ws + OFF_BN;
    float* hbuf = ws + OFF_H;
    float* Qf   = ws + OFF_QF;
    float* Kf   = ws + OFF_KF;
    float* rmaxp = ws + OFF_RMAX;
    float* rinvp = ws + OFF_RINV;
    float* cmaxp = ws + OFF_CMAX;
    float* cinvp = ws + OFF_CINV;

    unsigned short* Qhi = (unsigned short*)(ws + OFF_H);
    unsigned short* Qlo = Qhi + 8388608;
    unsigned short* Khi = (unsigned short*)(ws + OFF_QF);
    unsigned short* Klo = Khi + 8388608;

    float* outl = (float*)d_out;
    float* outr = outl + (size_t)2*CC*HWp;

    hipLaunchKernelGGL(bn_prep, dim3(1), dim3(64), 0, stream, bn_g, bn_b, bn_m, bn_v, bnss);
    hipLaunchKernelGGL(conv1_k, dim3(2048), dim3(256), 0, stream, x_left, w1, b1, bnss, hbuf);
    hipLaunchKernelGGL(conv2_k, dim3(1024), dim3(256), 0, stream, hbuf, x_left, w2, b2, bqw, bqb, bnss, Qf);
    hipLaunchKernelGGL(conv1_k, dim3(2048), dim3(256), 0, stream, x_right, w1, b1, bnss, hbuf);
    hipLaunchKernelGGL(conv2_k, dim3(1024), dim3(256), 0, stream, hbuf, x_right, w2, b2, bsw, bsb, bnss, Kf);
    // split (hbuf dead -> Qhi/Qlo region; Qf dead after csplit(Q) -> Khi/Klo region)
    hipLaunchKernelGGL(csplit, dim3(512), dim3(256), 0, stream, Qf, Qhi, Qlo, LOG2E);
    hipLaunchKernelGGL(csplit, dim3(512), dim3(256), 0, stream, Kf, Khi, Klo, 1.0f);
    hipLaunchKernelGGL(s1_stats, dim3(512), dim3(256), 0, stream, Qhi, Qlo, Khi, Klo, rmaxp, rinvp, cmaxp, cinvp);
    hipLaunchKernelGGL(s23_apply, dim3(512), dim3(256), 0, stream,
                       Qhi, Qlo, Khi, Klo, rmaxp, rinvp, cmaxp, cinvp, x_right, x_left, outl);
    hipLaunchKernelGGL(s23_apply, dim3(512), dim3(256), 0, stream,
                       Khi, Klo, Qhi, Qlo, cmaxp, cinvp, rmaxp, rinvp, x_left, x_right, outr);
}

// Round 4
// 703.636 us; speedup vs baseline: 3.0469x; 1.4693x over previous
//
#include <hip/hip_runtime.h>
#include <math.h>

#define CC 64
#define HH 256
#define WW 256
#define GC 16
#define HWp (HH*WW)
#define LOG2E 1.44269504088896340736f

typedef __attribute__((ext_vector_type(8))) short short8;
typedef __attribute__((ext_vector_type(4))) float f32x4;
typedef __attribute__((ext_vector_type(2))) unsigned long u64x2;

// ---------------- ws layout (bytes, all 256-aligned) ----------------
static constexpr size_t OFS_BNSS = 0;            // 128 f32
static constexpr size_t OFS_W1H  = 512;          // [64][160] bf16
static constexpr size_t OFS_W1L  = 20992;
static constexpr size_t OFS_W2H  = 41472;
static constexpr size_t OFS_W2L  = 61952;
static constexpr size_t OFS_WQH  = 82432;        // [64][128] bf16
static constexpr size_t OFS_WQL  = 98816;
static constexpr size_t OFS_WSH  = 115200;
static constexpr size_t OFS_WSL  = 131584;
static constexpr size_t OFS_RMAX = 147968;       // 512*256 f32 each
static constexpr size_t OFS_RINV = OFS_RMAX + 524288;
static constexpr size_t OFS_CMAX = OFS_RINV + 524288;
static constexpr size_t OFS_CINV = OFS_CMAX + 524288;
static constexpr size_t OFS_XBNH = OFS_CINV + 524288;          // [2][258][258][64] bf16
static constexpr size_t HALO_BYTES = (size_t)2*258*258*64*2;   // 17,040,384
static constexpr size_t OFS_XBNL = OFS_XBNH + HALO_BYTES;
static constexpr size_t OFS_HH   = OFS_XBNL + HALO_BYTES;
static constexpr size_t OFS_HL   = OFS_HH   + HALO_BYTES;
static constexpr size_t OFS_QH   = OFS_HL   + HALO_BYTES;      // [512][256][64] bf16
static constexpr size_t QK_BYTES = (size_t)512*256*64*2;
static constexpr size_t OFS_QL   = OFS_QH + QK_BYTES;
static constexpr size_t OFS_KH   = OFS_QL + QK_BYTES;
static constexpr size_t OFS_KL   = OFS_KH + QK_BYTES;

__device__ __forceinline__ unsigned short f2bf(float v) {
    unsigned int u = __float_as_uint(v);
    return (unsigned short)((u + 0x7fffu + ((u >> 16) & 1u)) >> 16);
}
__device__ __forceinline__ float bf2f(unsigned short h) {
    return __uint_as_float(((unsigned int)h) << 16);
}

// ---------------- weight/bn prep (1 block) ----------------
__global__ __launch_bounds__(256) void wprep(const float* __restrict__ g, const float* __restrict__ be,
        const float* __restrict__ mn, const float* __restrict__ va,
        const float* __restrict__ w1, const float* __restrict__ w2,
        const float* __restrict__ wq, const float* __restrict__ wsW,
        float* __restrict__ bnss,
        unsigned short* __restrict__ w1h, unsigned short* __restrict__ w1l,
        unsigned short* __restrict__ w2h, unsigned short* __restrict__ w2l,
        unsigned short* __restrict__ wqh, unsigned short* __restrict__ wql,
        unsigned short* __restrict__ wsh, unsigned short* __restrict__ wsl) {
    int t = threadIdx.x;
    if (t < 64) {
        float sc = g[t] / sqrtf(va[t] + 1e-5f);
        bnss[t] = sc;
        bnss[64 + t] = be[t] - mn[t] * sc;
    }
    // 3x3 grouped weights: [oc][k=tap*16+ic], k padded to 160
    for (int idx = t; idx < 64*160; idx += 256) {
        int oc = idx / 160, k = idx % 160;
        float v1 = 0.f, v2 = 0.f;
        if (k < 144) {
            int tap = k >> 4, ic = k & 15;
            int src = (oc*16 + ic)*9 + tap;
            v1 = w1[src]; v2 = w2[src];
        }
        unsigned short h1 = f2bf(v1), h2 = f2bf(v2);
        w1h[idx] = h1; w1l[idx] = f2bf(v1 - bf2f(h1));
        w2h[idx] = h2; w2l[idx] = f2bf(v2 - bf2f(h2));
    }
    // 1x1 weights duplicated over K=128 (conv-out | residual)
    for (int idx = t; idx < 64*128; idx += 256) {
        int oc = idx >> 7, k = idx & 127;
        float vq = wq[oc*64 + (k & 63)];
        float vs = wsW[oc*64 + (k & 63)];
        unsigned short hq = f2bf(vq), hs = f2bf(vs);
        wqh[idx] = hq; wql[idx] = f2bf(vq - bf2f(hq));
        wsh[idx] = hs; wsl[idx] = f2bf(vs - bf2f(hs));
    }
}

__global__ void zero_k(u64x2* __restrict__ p, size_t n) {
    size_t i = (size_t)blockIdx.x*blockDim.x + threadIdx.x;
    size_t st = (size_t)gridDim.x*blockDim.x;
    for (; i < n; i += st) p[i] = (u64x2){0ul, 0ul};
}

// ---------------- BN + NCHW->HWC(halo) hi/lo split ----------------
__global__ __launch_bounds__(256) void prep_k(const float* __restrict__ x,
        const float* __restrict__ bnss,
        unsigned short* __restrict__ xh, unsigned short* __restrict__ xl) {
    __shared__ float ld[64*256];
    __shared__ float sc[64], sh[64];
    int blk = blockIdx.x;
    int y = blk & 255, b = blk >> 8;
    int t = threadIdx.x;
    if (t < 64) { sc[t] = bnss[t]; sh[t] = bnss[64+t]; }
    for (int idx = t; idx < 16384; idx += 256) {
        int c = idx >> 8, xx = idx & 255;
        ld[c*256 + xx] = x[((size_t)(b*64 + c)*256 + y)*256 + xx];
    }
    __syncthreads();
    int px = t;
    size_t base = ((size_t)(b*258 + y+1)*258 + px+1)*64;
    #pragma unroll
    for (int ch = 0; ch < 4; ++ch) {
        short8 h0, h1, l0, l1;
        #pragma unroll
        for (int j = 0; j < 8; ++j) {
            int c = ch*16 + j;
            float f = ld[c*256 + px]*sc[c] + sh[c];
            unsigned short hh = f2bf(f);
            h0[j] = (short)hh; l0[j] = (short)f2bf(f - bf2f(hh));
        }
        #pragma unroll
        for (int j = 0; j < 8; ++j) {
            int c = ch*16 + 8 + j;
            float f = ld[c*256 + px]*sc[c] + sh[c];
            unsigned short hh = f2bf(f);
            h1[j] = (short)hh; l1[j] = (short)f2bf(f - bf2f(hh));
        }
        *(short8*)(xh + base + ch*16)     = h0;
        *(short8*)(xh + base + ch*16 + 8) = h1;
        *(short8*)(xl + base + ch*16)     = l0;
        *(short8*)(xl + base + ch*16 + 8) = l1;
    }
}

// ---------------- grouped 3x3 conv via MFMA, + leaky, -> h hi/lo ----------------
__global__ __launch_bounds__(256) void conv1_m(
        const unsigned short* __restrict__ inh, const unsigned short* __restrict__ inl,
        const unsigned short* __restrict__ wth, const unsigned short* __restrict__ wtl,
        const float* __restrict__ bias,
        unsigned short* __restrict__ oh, unsigned short* __restrict__ ol) {
    __shared__ unsigned short lh[256*72];
    __shared__ unsigned short ll[256*72];
    int blk = blockIdx.x;
    int y = blk & 255, b = blk >> 8;
    int t = threadIdx.x;
    int w = t >> 6, l = t & 63;
    int lr = l & 15, lg = l >> 4;

    f32x4 acc[4][4];
    #pragma unroll
    for (int g = 0; g < 4; ++g) {
        float bb = bias[g*16 + lr];
        #pragma unroll
        for (int mt = 0; mt < 4; ++mt) acc[mt][g] = (f32x4){bb,bb,bb,bb};
    }
    size_t lanebase = ((size_t)(b*258 + y)*258 + 64*w + lr)*64 + (lg & 1)*8;
    int koff[5];
    #pragma unroll
    for (int ks = 0; ks < 5; ++ks) {
        int tap = 2*ks + (lg >> 1);
        if (tap > 8) tap = 8;
        koff[ks] = ((tap/3)*258 + (tap%3))*64;
    }
    #pragma unroll
    for (int ks = 0; ks < 5; ++ks) {
        #pragma unroll
        for (int g = 0; g < 4; ++g) {
            short8 bh = *(const short8*)(wth + (g*16+lr)*160 + ks*32 + lg*8);
            short8 bl = *(const short8*)(wtl + (g*16+lr)*160 + ks*32 + lg*8);
            #pragma unroll
            for (int mt = 0; mt < 4; ++mt) {
                size_t off = lanebase + koff[ks] + mt*1024 + g*16;
                short8 ah = *(const short8*)(inh + off);
                short8 al = *(const short8*)(inl + off);
                acc[mt][g] = __builtin_amdgcn_mfma_f32_16x16x32_bf16(ah, bh, acc[mt][g], 0,0,0);
                acc[mt][g] = __builtin_amdgcn_mfma_f32_16x16x32_bf16(ah, bl, acc[mt][g], 0,0,0);
                acc[mt][g] = __builtin_amdgcn_mfma_f32_16x16x32_bf16(al, bh, acc[mt][g], 0,0,0);
            }
        }
    }
    // leaky + split -> LDS [px][72]
    #pragma unroll
    for (int mt = 0; mt < 4; ++mt)
        #pragma unroll
        for (int g = 0; g < 4; ++g)
            #pragma unroll
            for (int r = 0; r < 4; ++r) {
                float v = acc[mt][g][r];
                v = v > 0.f ? v : 0.1f*v;
                int px = 64*w + mt*16 + lg*4 + r;
                int oc = g*16 + lr;
                unsigned short hh = f2bf(v);
                lh[px*72 + oc] = hh;
                ll[px*72 + oc] = f2bf(v - bf2f(hh));
            }
    __syncthreads();
    size_t rowbase = ((size_t)(b*258 + y+1)*258 + 1)*64;
    #pragma unroll
    for (int i = 0; i < 8; ++i) {
        int cid = i*256 + t;
        int px = cid >> 3, part = cid & 7;
        *(short8*)(oh + rowbase + (size_t)px*64 + part*8) = *(short8*)&lh[px*72 + part*8];
        *(short8*)(ol + rowbase + (size_t)px*64 + part*8) = *(short8*)&ll[px*72 + part*8];
    }
}

// ---------------- grouped conv(h) + [1x1 over (conv|residual)] + center/scale/split ----------------
__global__ __launch_bounds__(256) void conv2_m(
        const unsigned short* __restrict__ hh, const unsigned short* __restrict__ hl,
        const unsigned short* __restrict__ xbh, const unsigned short* __restrict__ xbl,
        const unsigned short* __restrict__ wth, const unsigned short* __restrict__ wtl,
        const float* __restrict__ bias2,
        const unsigned short* __restrict__ wph, const unsigned short* __restrict__ wpl,
        const float* __restrict__ biasq, float scaleOut,
        unsigned short* __restrict__ Qh, unsigned short* __restrict__ Ql) {
    __shared__ unsigned short rs[4*9216];   // per-wave [64][72] hi + lo ; aliased as f32 qstage later
    __shared__ float red2[256];
    __shared__ float meanl[64];
    int blk = blockIdx.x;
    int y = blk & 255, b = blk >> 8;
    int t = threadIdx.x;
    int w = t >> 6, l = t & 63;
    int lr = l & 15, lg = l >> 4;

    // ---- phase A: grouped conv on h ----
    f32x4 acc[4][4];
    #pragma unroll
    for (int g = 0; g < 4; ++g) {
        float bb = bias2[g*16 + lr];
        #pragma unroll
        for (int mt = 0; mt < 4; ++mt) acc[mt][g] = (f32x4){bb,bb,bb,bb};
    }
    size_t lanebase = ((size_t)(b*258 + y)*258 + 64*w + lr)*64 + (lg & 1)*8;
    int koff[5];
    #pragma unroll
    for (int ks = 0; ks < 5; ++ks) {
        int tap = 2*ks + (lg >> 1);
        if (tap > 8) tap = 8;
        koff[ks] = ((tap/3)*258 + (tap%3))*64;
    }
    #pragma unroll
    for (int ks = 0; ks < 5; ++ks) {
        #pragma unroll
        for (int g = 0; g < 4; ++g) {
            short8 bh = *(const short8*)(wth + (g*16+lr)*160 + ks*32 + lg*8);
            short8 bl = *(const short8*)(wtl + (g*16+lr)*160 + ks*32 + lg*8);
            #pragma unroll
            for (int mt = 0; mt < 4; ++mt) {
                size_t off = lanebase + koff[ks] + mt*1024 + g*16;
                short8 ah = *(const short8*)(hh + off);
                short8 al = *(const short8*)(hl + off);
                acc[mt][g] = __builtin_amdgcn_mfma_f32_16x16x32_bf16(ah, bh, acc[mt][g], 0,0,0);
                acc[mt][g] = __builtin_amdgcn_mfma_f32_16x16x32_bf16(ah, bl, acc[mt][g], 0,0,0);
                acc[mt][g] = __builtin_amdgcn_mfma_f32_16x16x32_bf16(al, bh, acc[mt][g], 0,0,0);
            }
        }
    }
    // stage conv-out hi/lo into per-wave LDS [64px][72]
    unsigned short* rsw = rs + w*9216;
    #pragma unroll
    for (int mt = 0; mt < 4; ++mt)
        #pragma unroll
        for (int g = 0; g < 4; ++g)
            #pragma unroll
            for (int r = 0; r < 4; ++r) {
                float v = acc[mt][g][r];
                int pxl = mt*16 + lg*4 + r;
                int oc = g*16 + lr;
                unsigned short hv = f2bf(v);
                rsw[pxl*72 + oc] = hv;
                rsw[4608 + pxl*72 + oc] = f2bf(v - bf2f(hv));
            }
    // ---- phase B: 1x1 GEMM, K=128 = (conv-out 64 | residual xbn 64) ----
    f32x4 acc2[4][4];
    #pragma unroll
    for (int nt = 0; nt < 4; ++nt) {
        float bb = biasq[nt*16 + lr];
        #pragma unroll
        for (int mt = 0; mt < 4; ++mt) acc2[mt][nt] = (f32x4){bb,bb,bb,bb};
    }
    size_t cbase = ((size_t)(b*258 + y+1)*258 + 64*w + lr + 1)*64 + lg*8;
    #pragma unroll
    for (int ks = 0; ks < 4; ++ks) {
        short8 Ah[4], Al[4];
        #pragma unroll
        for (int mt = 0; mt < 4; ++mt) {
            if (ks < 2) {
                Ah[mt] = *(short8*)&rsw[(mt*16+lr)*72 + ks*32 + lg*8];
                Al[mt] = *(short8*)&rsw[4608 + (mt*16+lr)*72 + ks*32 + lg*8];
            } else {
                size_t off = cbase + (size_t)mt*1024 + (ks-2)*32;
                Ah[mt] = *(const short8*)(xbh + off);
                Al[mt] = *(const short8*)(xbl + off);
            }
        }
        #pragma unroll
        for (int nt = 0; nt < 4; ++nt) {
            short8 Bh = *(const short8*)(wph + (nt*16+lr)*128 + ks*32 + lg*8);
            short8 Bl = *(const short8*)(wpl + (nt*16+lr)*128 + ks*32 + lg*8);
            #pragma unroll
            for (int mt = 0; mt < 4; ++mt) {
                acc2[mt][nt] = __builtin_amdgcn_mfma_f32_16x16x32_bf16(Ah[mt], Bh, acc2[mt][nt], 0,0,0);
                acc2[mt][nt] = __builtin_amdgcn_mfma_f32_16x16x32_bf16(Ah[mt], Bl, acc2[mt][nt], 0,0,0);
                acc2[mt][nt] = __builtin_amdgcn_mfma_f32_16x16x32_bf16(Al[mt], Bh, acc2[mt][nt], 0,0,0);
            }
        }
    }
    __syncthreads();          // all waves done with rs before aliasing
    // ---- phase C: mean-center over width, scale, split ----
    float* qs = (float*)rs;   // [256][68]
    #pragma unroll
    for (int mt = 0; mt < 4; ++mt)
        #pragma unroll
        for (int nt = 0; nt < 4; ++nt)
            #pragma unroll
            for (int r = 0; r < 4; ++r)
                qs[(64*w + mt*16 + lg*4 + r)*68 + nt*16 + lr] = acc2[mt][nt][r];
    __syncthreads();
    {
        int c = t & 63, seg = t >> 6;
        float s = 0.f;
        for (int i = 0; i < 64; ++i) s += qs[(seg*64 + i)*68 + c];
        red2[t] = s;
    }
    __syncthreads();
    if (t < 64) meanl[t] = (red2[t] + red2[64+t] + red2[128+t] + red2[192+t]) * (1.f/256.f);
    __syncthreads();
    int n = b*256 + y;
    size_t obase = ((size_t)n*256 + t)*64;
    #pragma unroll
    for (int ch = 0; ch < 4; ++ch) {
        short8 h0, h1, l0, l1;
        #pragma unroll
        for (int j = 0; j < 8; ++j) {
            int c = ch*16 + j;
            float f = (qs[t*68 + c] - meanl[c]) * scaleOut;
            unsigned short hv = f2bf(f);
            h0[j] = (short)hv; l0[j] = (short)f2bf(f - bf2f(hv));
        }
        #pragma unroll
        for (int j = 0; j < 8; ++j) {
            int c = ch*16 + 8 + j;
            float f = (qs[t*68 + c] - meanl[c]) * scaleOut;
            unsigned short hv = f2bf(f);
            h1[j] = (short)hv; l1[j] = (short)f2bf(f - bf2f(hv));
        }
        *(short8*)(Qh + obase + ch*16)     = h0;
        *(short8*)(Qh + obase + ch*16 + 8) = h1;
        *(short8*)(Ql + obase + ch*16)     = l0;
        *(short8*)(Ql + obase + ch*16 + 8) = l1;
    }
}

// ---------------- attention (unchanged from R2) ----------------
__global__ __launch_bounds__(256) void s1_stats(
        const unsigned short* __restrict__ Qhi, const unsigned short* __restrict__ Qlo,
        const unsigned short* __restrict__ Khi, const unsigned short* __restrict__ Klo,
        float* __restrict__ rmax, float* __restrict__ rinv,
        float* __restrict__ cmax, float* __restrict__ cinv) {
    __shared__ float colred[4][256][2];
    int n = blockIdx.x;
    int t = threadIdx.x;
    int w = t >> 6, l = t & 63;
    int lr = l & 15, lg = l >> 4;
    const size_t qb = (size_t)n * 16384;

    short8 qh[4][2], ql[4][2];
    #pragma unroll
    for (int rf = 0; rf < 4; ++rf)
        #pragma unroll
        for (int ks = 0; ks < 2; ++ks) {
            size_t a = qb + (size_t)(w*64 + rf*16 + lr)*64 + ks*32 + lg*8;
            qh[rf][ks] = *reinterpret_cast<const short8*>(Qhi + a);
            ql[rf][ks] = *reinterpret_cast<const short8*>(Qlo + a);
        }
    float mrow[4][4], srow[4][4];
    #pragma unroll
    for (int rf = 0; rf < 4; ++rf)
        #pragma unroll
        for (int r = 0; r < 4; ++r) { mrow[rf][r] = -3.0e38f; srow[rf][r] = 0.f; }

    for (int jt = 0; jt < 8; ++jt) {
        short8 kh[2][2], kl[2][2];
        #pragma unroll
        for (int cf = 0; cf < 2; ++cf)
            #pragma unroll
            for (int ks = 0; ks < 2; ++ks) {
                size_t a = qb + (size_t)(jt*32 + cf*16 + lr)*64 + ks*32 + lg*8;
                kh[cf][ks] = *reinterpret_cast<const short8*>(Khi + a);
                kl[cf][ks] = *reinterpret_cast<const short8*>(Klo + a);
            }
        f32x4 acc[4][2];
        #pragma unroll
        for (int rf = 0; rf < 4; ++rf)
            #pragma unroll
            for (int cf = 0; cf < 2; ++cf) acc[rf][cf] = (f32x4){0.f,0.f,0.f,0.f};
        #pragma unroll
        for (int ks = 0; ks < 2; ++ks)
            #pragma unroll
            for (int rf = 0; rf < 4; ++rf)
                #pragma unroll
                for (int cf = 0; cf < 2; ++cf) {
                    acc[rf][cf] = __builtin_amdgcn_mfma_f32_16x16x32_bf16(qh[rf][ks], kh[cf][ks], acc[rf][cf], 0,0,0);
                    acc[rf][cf] = __builtin_amdgcn_mfma_f32_16x16x32_bf16(qh[rf][ks], kl[cf][ks], acc[rf][cf], 0,0,0);
                    acc[rf][cf] = __builtin_amdgcn_mfma_f32_16x16x32_bf16(ql[rf][ks], kh[cf][ks], acc[rf][cf], 0,0,0);
                }
        #pragma unroll
        for (int rf = 0; rf < 4; ++rf)
            #pragma unroll
            for (int r = 0; r < 4; ++r) {
                float e0 = acc[rf][0][r], e1 = acc[rf][1][r];
                float m2 = fmaxf(mrow[rf][r], fmaxf(e0, e1));
                srow[rf][r] = srow[rf][r]*exp2f(mrow[rf][r]-m2) + exp2f(e0-m2) + exp2f(e1-m2);
                mrow[rf][r] = m2;
            }
        #pragma unroll
        for (int cf = 0; cf < 2; ++cf) {
            float m = acc[0][cf][0];
            #pragma unroll
            for (int rf = 0; rf < 4; ++rf)
                #pragma unroll
                for (int r = 0; r < 4; ++r) m = fmaxf(m, acc[rf][cf][r]);
            float s = 0.f;
            #pragma unroll
            for (int rf = 0; rf < 4; ++rf)
                #pragma unroll
                for (int r = 0; r < 4; ++r) s += exp2f(acc[rf][cf][r] - m);
            #pragma unroll
            for (int mask = 16; mask <= 32; mask <<= 1) {
                float om = __shfl_xor(m, mask);
                float os = __shfl_xor(s, mask);
                float m2 = fmaxf(m, om);
                s = s*exp2f(m-m2) + os*exp2f(om-m2);
                m = m2;
            }
            if (lg == 0) {
                int j = jt*32 + cf*16 + lr;
                colred[w][j][0] = m;
                colred[w][j][1] = s;
            }
        }
    }
    #pragma unroll
    for (int rf = 0; rf < 4; ++rf)
        #pragma unroll
        for (int r = 0; r < 4; ++r) {
            float m = mrow[rf][r], s = srow[rf][r];
            #pragma unroll
            for (int mask = 1; mask <= 8; mask <<= 1) {
                float om = __shfl_xor(m, mask);
                float os = __shfl_xor(s, mask);
                float m2 = fmaxf(m, om);
                s = s*exp2f(m-m2) + os*exp2f(om-m2);
                m = m2;
            }
            if (lr == 0) {
                int row = w*64 + rf*16 + lg*4 + r;
                rmax[n*256 + row] = m;
                rinv[n*256 + row] = 1.f / s;
            }
        }
    __syncthreads();
    {
        int j = t;
        float m = colred[0][j][0], s = colred[0][j][1];
        #pragma unroll
        for (int w2_ = 1; w2_ < 4; ++w2_) {
            float om = colred[w2_][j][0], os = colred[w2_][j][1];
            float m2 = fmaxf(m, om);
            s = s*exp2f(m-m2) + os*exp2f(om-m2);
            m = m2;
        }
        cmax[n*256 + j] = m;
        cinv[n*256 + j] = 1.f / s;
    }
}

__global__ __launch_bounds__(256) void s23_apply(
        const unsigned short* __restrict__ Ahi, const unsigned short* __restrict__ Alo,
        const unsigned short* __restrict__ Bhi, const unsigned short* __restrict__ Blo,
        const float* __restrict__ rowmax, const float* __restrict__ rowinv,
        const float* __restrict__ colmax, const float* __restrict__ colinv,
        const float* __restrict__ Xpv, const float* __restrict__ Xblend,
        float* __restrict__ outp) {
    __shared__ unsigned short pa[256][40];
    __shared__ unsigned short pb[256][40];
    __shared__ float vred[4][256];
    __shared__ float cmax_l[256], cinv_l[256];
    __shared__ float vfin[256];
    int n = blockIdx.x;
    int y = n & 255, b = n >> 8;
    int t = threadIdx.x;
    int w = t >> 6, l = t & 63;
    int lr = l & 15, lg = l >> 4;
    const size_t qb = (size_t)n * 16384;

    cmax_l[t] = colmax[n*256 + t];
    cinv_l[t] = colinv[n*256 + t];
    for (int q = t; q < 1024; q += 256) ((float*)vred)[q] = 0.f;

    float rmx[4][4], rin[4][4];
    #pragma unroll
    for (int rf = 0; rf < 4; ++rf)
        #pragma unroll
        for (int r = 0; r < 4; ++r) {
            int row = w*64 + rf*16 + lg*4 + r;
            rmx[rf][r] = rowmax[n*256 + row];
            rin[rf][r] = rowinv[n*256 + row];
        }
    short8 ah[4][2], al[4][2];
    #pragma unroll
    for (int rf = 0; rf < 4; ++rf)
        #pragma unroll
        for (int ks = 0; ks < 2; ++ks) {
            size_t a = qb + (size_t)(w*64 + rf*16 + lr)*64 + ks*32 + lg*8;
            ah[rf][ks] = *reinterpret_cast<const short8*>(Ahi + a);
            al[rf][ks] = *reinterpret_cast<const short8*>(Alo + a);
        }
    f32x4 pv[4][4];
    #pragma unroll
    for (int rf = 0; rf < 4; ++rf)
        #pragma unroll
        for (int cf = 0; cf < 4; ++cf) pv[rf][cf] = (f32x4){0.f,0.f,0.f,0.f};
    float vacc[6];
    #pragma unroll
    for (int s = 0; s < 6; ++s) vacc[s] = 0.f;

    const float* xpvb = Xpv + (size_t)b*CC*HWp + (size_t)y*WW;
    __syncthreads();

    for (int jt = 0; jt < 8; ++jt) {
        short8 bh[2][2], bl[2][2];
        #pragma unroll
        for (int cf = 0; cf < 2; ++cf)
            #pragma unroll
            for (int ks = 0; ks < 2; ++ks) {
                size_t a = qb + (size_t)(jt*32 + cf*16 + lr)*64 + ks*32 + lg*8;
                bh[cf][ks] = *reinterpret_cast<const short8*>(Bhi + a);
                bl[cf][ks] = *reinterpret_cast<const short8*>(Blo + a);
            }
        f32x4 acc[4][2];
        #pragma unroll
        for (int rf = 0; rf < 4; ++rf)
            #pragma unroll
            for (int cf = 0; cf < 2; ++cf) acc[rf][cf] = (f32x4){0.f,0.f,0.f,0.f};
        #pragma unroll
        for (int ks = 0; ks < 2; ++ks)
            #pragma unroll
            for (int rf = 0; rf < 4; ++rf)
                #pragma unroll
                for (int cf = 0; cf < 2; ++cf) {
                    acc[rf][cf] = __builtin_amdgcn_mfma_f32_16x16x32_bf16(ah[rf][ks], bh[cf][ks], acc[rf][cf], 0,0,0);
                    acc[rf][cf] = __builtin_amdgcn_mfma_f32_16x16x32_bf16(ah[rf][ks], bl[cf][ks], acc[rf][cf], 0,0,0);
                    acc[rf][cf] = __builtin_amdgcn_mfma_f32_16x16x32_bf16(al[rf][ks], bh[cf][ks], acc[rf][cf], 0,0,0);
                }
        #pragma unroll
        for (int rf = 0; rf < 4; ++rf)
            #pragma unroll
            for (int cf = 0; cf < 2; ++cf) {
                int col = cf*16 + lr;
                float cm = cmax_l[jt*32 + col];
                float ci = cinv_l[jt*32 + col];
                #pragma unroll
                for (int r = 0; r < 4; ++r) {
                    float e = acc[rf][cf][r];
                    int row = w*64 + rf*16 + lg*4 + r;
                    pa[row][col] = f2bf(exp2f(e - rmx[rf][r]) * rin[rf][r]);
                    pb[row][col] = f2bf(exp2f(e - cm) * ci);
                }
            }
        __syncthreads();
        #pragma unroll
        for (int Tl = 0; Tl < 4; ++Tl) {
            int T = w*4 + Tl;
            short8 afr = *reinterpret_cast<short8*>(&pa[T*16 + lr][lg*8]);
            #pragma unroll
            for (int dT = -1; dT <= 1; ++dT) {
                int Tp = T + dT;
                if (Tp < 0 || Tp > 15) continue;
                short8 bfr = *reinterpret_cast<short8*>(&pb[Tp*16 + lr][lg*8]);
                f32x4 wacc = (f32x4){0.f,0.f,0.f,0.f};
                wacc = __builtin_amdgcn_mfma_f32_16x16x32_bf16(afr, bfr, wacc, 0,0,0);
                #pragma unroll
                for (int r = 0; r < 4; ++r) {
                    int diff = lg*4 + r - lr - 16*dT;
                    if (diff >= -2 && diff <= 2) vacc[Tl + dT + 1] += wacc[r];
                }
            }
        }
        #pragma unroll
        for (int cf4 = 0; cf4 < 4; ++cf4) {
            const float* xp = xpvb + (size_t)(cf4*16 + lr)*HWp + jt*32 + lg*8;
            float4 xv0 = *(const float4*)(xp);
            float4 xv1 = *(const float4*)(xp + 4);
            short8 xf;
            xf[0] = (short)f2bf(xv0.x); xf[1] = (short)f2bf(xv0.y);
            xf[2] = (short)f2bf(xv0.z); xf[3] = (short)f2bf(xv0.w);
            xf[4] = (short)f2bf(xv1.x); xf[5] = (short)f2bf(xv1.y);
            xf[6] = (short)f2bf(xv1.z); xf[7] = (short)f2bf(xv1.w);
            #pragma unroll
            for (int rf = 0; rf < 4; ++rf) {
                short8 paf = *reinterpret_cast<short8*>(&pa[w*64 + rf*16 + lr][lg*8]);
                pv[rf][cf4] = __builtin_amdgcn_mfma_f32_16x16x32_bf16(paf, xf, pv[rf][cf4], 0,0,0);
            }
        }
        __syncthreads();
    }
    #pragma unroll
    for (int s = 0; s < 6; ++s) {
        float v = vacc[s];
        v += __shfl_xor(v, 16);
        v += __shfl_xor(v, 32);
        if (lg == 0) {
            int i = (w*4 - 1 + s)*16 + lr;
            if (i >= 0 && i < 256) vred[w][i] = v;
        }
    }
    __syncthreads();
    vfin[t] = tanhf(5.f * (vred[0][t] + vred[1][t] + vred[2][t] + vred[3][t]));
    __syncthreads();
    const float* xbb = Xblend + (size_t)b*CC*HWp + (size_t)y*WW;
    float* ob = outp + (size_t)b*CC*HWp + (size_t)y*WW;
    #pragma unroll
    for (int rf = 0; rf < 4; ++rf)
        #pragma unroll
        for (int r = 0; r < 4; ++r) {
            int row = w*64 + rf*16 + lg*4 + r;
            float vt = vfin[row];
            #pragma unroll
            for (int cf4 = 0; cf4 < 4; ++cf4) {
                int c = cf4*16 + lr;
                size_t ga = (size_t)c*HWp + row;
                float xv = xbb[ga];
                ob[ga] = xv + vt * (pv[rf][cf4][r] - xv);
            }
        }
}

extern "C" void kernel_launch(void* const* d_in, const int* in_sizes, int n_in,
                              void* d_out, int out_size, void* d_ws, size_t ws_size,
                              hipStream_t stream) {
    const float* x_left  = (const float*)d_in[0];
    const float* x_right = (const float*)d_in[1];
    const float* bn_g = (const float*)d_in[4];
    const float* bn_b = (const float*)d_in[5];
    const float* bn_m = (const float*)d_in[6];
    const float* bn_v = (const float*)d_in[7];
    const float* w1  = (const float*)d_in[8];
    const float* b1  = (const float*)d_in[9];
    const float* w2  = (const float*)d_in[10];
    const float* b2  = (const float*)d_in[11];
    const float* bqw = (const float*)d_in[12];
    const float* bqb = (const float*)d_in[13];
    const float* bsw = (const float*)d_in[14];
    const float* bsb = (const float*)d_in[15];

    char* base = (char*)d_ws;
    float* bnss = (float*)(base + OFS_BNSS);
    unsigned short* w1h = (unsigned short*)(base + OFS_W1H);
    unsigned short* w1l = (unsigned short*)(base + OFS_W1L);
    unsigned short* w2h = (unsigned short*)(base + OFS_W2H);
    unsigned short* w2l = (unsigned short*)(base + OFS_W2L);
    unsigned short* wqh = (unsigned short*)(base + OFS_WQH);
    unsigned short* wql = (unsigned short*)(base + OFS_WQL);
    unsigned short* wsh = (unsigned short*)(base + OFS_WSH);
    unsigned short* wsl = (unsigned short*)(base + OFS_WSL);
    float* rmaxp = (float*)(base + OFS_RMAX);
    float* rinvp = (float*)(base + OFS_RINV);
    float* cmaxp = (float*)(base + OFS_CMAX);
    float* cinvp = (float*)(base + OFS_CINV);
    unsigned short* xbh = (unsigned short*)(base + OFS_XBNH);
    unsigned short* xbl = (unsigned short*)(base + OFS_XBNL);
    unsigned short* hh  = (unsigned short*)(base + OFS_HH);
    unsigned short* hl  = (unsigned short*)(base + OFS_HL);
    unsigned short* Qh  = (unsigned short*)(base + OFS_QH);
    unsigned short* Ql  = (unsigned short*)(base + OFS_QL);
    unsigned short* Kh  = (unsigned short*)(base + OFS_KH);
    unsigned short* Kl  = (unsigned short*)(base + OFS_KL);

    float* outl = (float*)d_out;
    float* outr = outl + (size_t)2*CC*HWp;

    hipLaunchKernelGGL(wprep, dim3(1), dim3(256), 0, stream,
                       bn_g, bn_b, bn_m, bn_v, w1, w2, bqw, bsw,
                       bnss, w1h, w1l, w2h, w2l, wqh, wql, wsh, wsl);
    // zero the 4 halo'd activation buffers (xbh,xbl,hh,hl are contiguous)
    hipLaunchKernelGGL(zero_k, dim3(2048), dim3(256), 0, stream,
                       (u64x2*)(base + OFS_XBNH), (size_t)(4*HALO_BYTES/16));
    // left -> Q
    hipLaunchKernelGGL(prep_k,  dim3(512), dim3(256), 0, stream, x_left, bnss, xbh, xbl);
    hipLaunchKernelGGL(conv1_m, dim3(512), dim3(256), 0, stream, xbh, xbl, w1h, w1l, b1, hh, hl);
    hipLaunchKernelGGL(conv2_m, dim3(512), dim3(256), 0, stream, hh, hl, xbh, xbl,
                       w2h, w2l, b2, wqh, wql, bqb, LOG2E, Qh, Ql);
    // right -> K
    hipLaunchKernelGGL(prep_k,  dim3(512), dim3(256), 0, stream, x_right, bnss, xbh, xbl);
    hipLaunchKernelGGL(conv1_m, dim3(512), dim3(256), 0, stream, xbh, xbl, w1h, w1l, b1, hh, hl);
    hipLaunchKernelGGL(conv2_m, dim3(512), dim3(256), 0, stream, hh, hl, xbh, xbl,
                       w2h, w2l, b2, wsh, wsl, bsb, 1.0f, Kh, Kl);
    // attention
    hipLaunchKernelGGL(s1_stats, dim3(512), dim3(256), 0, stream, Qh, Ql, Kh, Kl, rmaxp, rinvp, cmaxp, cinvp);
    hipLaunchKernelGGL(s23_apply, dim3(512), dim3(256), 0, stream,
                       Qh, Ql, Kh, Kl, rmaxp, rinvp, cmaxp, cinvp, x_right, x_left, outl);
    hipLaunchKernelGGL(s23_apply, dim3(512), dim3(256), 0, stream,
                       Kh, Kl, Qh, Ql, cmaxp, cinvp, rmaxp, rinvp, x_left, x_right, outr);
}

// Round 5
// 580.644 us; speedup vs baseline: 3.6923x; 1.2118x over previous
//
#include <hip/hip_runtime.h>
#include <math.h>

#define CC 64
#define HH 256
#define WW 256
#define GC 16
#define HWp (HH*WW)
#define LOG2E 1.44269504088896340736f

typedef __attribute__((ext_vector_type(8))) short short8;
typedef __attribute__((ext_vector_type(4))) float f32x4;

// ---------------- ws layout (bytes, all 256-aligned) ----------------
static constexpr size_t OFS_BNSS = 0;            // 128 f32
static constexpr size_t OFS_W1H  = 512;          // [64][160] bf16
static constexpr size_t OFS_W1L  = 20992;
static constexpr size_t OFS_W2H  = 41472;
static constexpr size_t OFS_W2L  = 61952;
static constexpr size_t OFS_WQH  = 82432;        // [64][128] bf16
static constexpr size_t OFS_WQL  = 98816;
static constexpr size_t OFS_WSH  = 115200;
static constexpr size_t OFS_WSL  = 131584;
static constexpr size_t OFS_RMAX = 147968;       // 512*256 f32 each
static constexpr size_t OFS_RINV = OFS_RMAX + 524288;
static constexpr size_t OFS_CMAX = OFS_RINV + 524288;
static constexpr size_t OFS_CINV = OFS_CMAX + 524288;
static constexpr size_t OFS_XBNH = OFS_CINV + 524288;          // [2][258][258][64] bf16
static constexpr size_t HALO_BYTES = (size_t)2*258*258*64*2;   // 17,040,384
static constexpr size_t HALO_U16  = HALO_BYTES/2;
static constexpr size_t OFS_XBNL = OFS_XBNH + HALO_BYTES;
static constexpr size_t OFS_HH   = OFS_XBNL + HALO_BYTES;
static constexpr size_t OFS_HL   = OFS_HH   + HALO_BYTES;
static constexpr size_t OFS_QH   = OFS_HL   + HALO_BYTES;      // [512][256][64] bf16
static constexpr size_t QK_BYTES = (size_t)512*256*64*2;
static constexpr size_t OFS_QL   = OFS_QH + QK_BYTES;
static constexpr size_t OFS_KH   = OFS_QL + QK_BYTES;
static constexpr size_t OFS_KL   = OFS_KH + QK_BYTES;
static constexpr size_t XB_BYTES = (size_t)2*64*256*256*2;     // x in bf16 CHW
static constexpr size_t OFS_XLB  = OFS_KL + QK_BYTES;
static constexpr size_t OFS_XRB  = OFS_XLB + XB_BYTES;

__device__ __forceinline__ unsigned short f2bf(float v) {
    unsigned int u = __float_as_uint(v);
    return (unsigned short)((u + 0x7fffu + ((u >> 16) & 1u)) >> 16);
}
__device__ __forceinline__ float bf2f(unsigned short h) {
    return __uint_as_float(((unsigned int)h) << 16);
}

// ---------------- weight/bn prep (1 block) ----------------
__global__ __launch_bounds__(256) void wprep(const float* __restrict__ g, const float* __restrict__ be,
        const float* __restrict__ mn, const float* __restrict__ va,
        const float* __restrict__ w1, const float* __restrict__ w2,
        const float* __restrict__ wq, const float* __restrict__ wsW,
        float* __restrict__ bnss,
        unsigned short* __restrict__ w1h, unsigned short* __restrict__ w1l,
        unsigned short* __restrict__ w2h, unsigned short* __restrict__ w2l,
        unsigned short* __restrict__ wqh, unsigned short* __restrict__ wql,
        unsigned short* __restrict__ wsh, unsigned short* __restrict__ wsl) {
    int t = threadIdx.x;
    if (t < 64) {
        float sc = g[t] / sqrtf(va[t] + 1e-5f);
        bnss[t] = sc;
        bnss[64 + t] = be[t] - mn[t] * sc;
    }
    for (int idx = t; idx < 64*160; idx += 256) {
        int oc = idx / 160, k = idx % 160;
        float v1 = 0.f, v2 = 0.f;
        if (k < 144) {
            int tap = k >> 4, ic = k & 15;
            int src = (oc*16 + ic)*9 + tap;
            v1 = w1[src]; v2 = w2[src];
        }
        unsigned short h1 = f2bf(v1), h2 = f2bf(v2);
        w1h[idx] = h1; w1l[idx] = f2bf(v1 - bf2f(h1));
        w2h[idx] = h2; w2l[idx] = f2bf(v2 - bf2f(h2));
    }
    for (int idx = t; idx < 64*128; idx += 256) {
        int oc = idx >> 7, k = idx & 127;
        float vq = wq[oc*64 + (k & 63)];
        float vs = wsW[oc*64 + (k & 63)];
        unsigned short hq = f2bf(vq), hs = f2bf(vs);
        wqh[idx] = hq; wql[idx] = f2bf(vq - bf2f(hq));
        wsh[idx] = hs; wsl[idx] = f2bf(vs - bf2f(hs));
    }
}

// zero only the 1-px halo border of the 4 halo'd buffers (8 slabs of [258][258][64])
__global__ __launch_bounds__(256) void zhalo(unsigned short* __restrict__ p) {
    int idx = blockIdx.x*256 + threadIdx.x;
    if (idx >= 65792) return;          // 8 slabs * 1028 pos * 8 ch-groups
    int ch8 = idx & 7;
    int rest = idx >> 3;
    int slab = rest / 1028;
    int pos  = rest % 1028;
    size_t slabbase = (size_t)slab * 4260096;   // 258*258*64
    int y, x;
    if (pos < 258)      { y = 0;   x = pos; }
    else if (pos < 516) { y = 257; x = pos - 258; }
    else if (pos < 772) { y = pos - 516 + 1; x = 0; }
    else                { y = pos - 772 + 1; x = 257; }
    size_t off = slabbase + ((size_t)y*258 + x)*64 + ch8*8;
    *(short8*)(p + off) = (short8){0,0,0,0,0,0,0,0};
}

// ---------------- BN + NCHW->HWC(halo) hi/lo split, + raw-x bf16 CHW ----------------
__global__ __launch_bounds__(512) void prep_k(const float* __restrict__ x,
        const float* __restrict__ bnss,
        unsigned short* __restrict__ xh, unsigned short* __restrict__ xl,
        unsigned short* __restrict__ xb16) {
    __shared__ float ld[64*256];
    __shared__ float sc[64], sh[64];
    int blk = blockIdx.x;
    int y = blk & 255, b = blk >> 8;
    int t = threadIdx.x;
    if (t < 64) { sc[t] = bnss[t]; sh[t] = bnss[64+t]; }
    for (int idx = t; idx < 16384; idx += 512) {
        int c = idx >> 8, xx = idx & 255;
        float v = x[((size_t)(b*64 + c)*256 + y)*256 + xx];
        ld[c*256 + xx] = v;
        xb16[((size_t)(b*64 + c)*256 + y)*256 + xx] = f2bf(v);
    }
    __syncthreads();
    int px = t >> 1, half = (t & 1) * 32;
    size_t base = ((size_t)(b*258 + y+1)*258 + px+1)*64;
    #pragma unroll
    for (int cc = 0; cc < 2; ++cc) {
        int cb = half + cc*16;
        short8 h0, h1, l0, l1;
        #pragma unroll
        for (int j = 0; j < 8; ++j) {
            int c = cb + j;
            float f = ld[c*256 + px]*sc[c] + sh[c];
            unsigned short hh = f2bf(f);
            h0[j] = (short)hh; l0[j] = (short)f2bf(f - bf2f(hh));
        }
        #pragma unroll
        for (int j = 0; j < 8; ++j) {
            int c = cb + 8 + j;
            float f = ld[c*256 + px]*sc[c] + sh[c];
            unsigned short hh = f2bf(f);
            h1[j] = (short)hh; l1[j] = (short)f2bf(f - bf2f(hh));
        }
        *(short8*)(xh + base + cb)     = h0;
        *(short8*)(xh + base + cb + 8) = h1;
        *(short8*)(xl + base + cb)     = l0;
        *(short8*)(xl + base + cb + 8) = l1;
    }
}

// ---------------- grouped 3x3 conv via MFMA, + leaky, -> h hi/lo (512 thr, 8 waves x 32px) ----
__global__ __launch_bounds__(512) void conv1_m(
        const unsigned short* __restrict__ inh, const unsigned short* __restrict__ inl,
        const unsigned short* __restrict__ wth, const unsigned short* __restrict__ wtl,
        const float* __restrict__ bias,
        unsigned short* __restrict__ oh, unsigned short* __restrict__ ol) {
    __shared__ unsigned short lh[256*72];
    __shared__ unsigned short ll[256*72];
    int blk = blockIdx.x;
    int y = blk & 255, b = blk >> 8;
    int t = threadIdx.x;
    int w = t >> 6, l = t & 63;
    int lr = l & 15, lg = l >> 4;

    f32x4 acc[2][4];
    #pragma unroll
    for (int g = 0; g < 4; ++g) {
        float bb = bias[g*16 + lr];
        #pragma unroll
        for (int mt = 0; mt < 2; ++mt) acc[mt][g] = (f32x4){bb,bb,bb,bb};
    }
    size_t lanebase = ((size_t)(b*258 + y)*258 + 32*w + lr)*64 + (lg & 1)*8;
    int koff[5];
    #pragma unroll
    for (int ks = 0; ks < 5; ++ks) {
        int tap = 2*ks + (lg >> 1);
        if (tap > 8) tap = 8;
        koff[ks] = ((tap/3)*258 + (tap%3))*64;
    }
    #pragma unroll
    for (int ks = 0; ks < 5; ++ks) {
        #pragma unroll
        for (int g = 0; g < 4; ++g) {
            short8 bh = *(const short8*)(wth + (g*16+lr)*160 + ks*32 + lg*8);
            short8 bl = *(const short8*)(wtl + (g*16+lr)*160 + ks*32 + lg*8);
            #pragma unroll
            for (int mt = 0; mt < 2; ++mt) {
                size_t off = lanebase + koff[ks] + mt*1024 + g*16;
                short8 ah = *(const short8*)(inh + off);
                short8 al = *(const short8*)(inl + off);
                acc[mt][g] = __builtin_amdgcn_mfma_f32_16x16x32_bf16(ah, bh, acc[mt][g], 0,0,0);
                acc[mt][g] = __builtin_amdgcn_mfma_f32_16x16x32_bf16(ah, bl, acc[mt][g], 0,0,0);
                acc[mt][g] = __builtin_amdgcn_mfma_f32_16x16x32_bf16(al, bh, acc[mt][g], 0,0,0);
            }
        }
    }
    #pragma unroll
    for (int mt = 0; mt < 2; ++mt)
        #pragma unroll
        for (int g = 0; g < 4; ++g)
            #pragma unroll
            for (int r = 0; r < 4; ++r) {
                float v = acc[mt][g][r];
                v = v > 0.f ? v : 0.1f*v;
                int px = 32*w + mt*16 + lg*4 + r;
                int oc = g*16 + lr;
                unsigned short hh = f2bf(v);
                lh[px*72 + oc] = hh;
                ll[px*72 + oc] = f2bf(v - bf2f(hh));
            }
    __syncthreads();
    size_t rowbase = ((size_t)(b*258 + y+1)*258 + 1)*64;
    #pragma unroll
    for (int i = 0; i < 4; ++i) {
        int cid = i*512 + t;
        int px = cid >> 3, part = cid & 7;
        *(short8*)(oh + rowbase + (size_t)px*64 + part*8) = *(short8*)&lh[px*72 + part*8];
        *(short8*)(ol + rowbase + (size_t)px*64 + part*8) = *(short8*)&ll[px*72 + part*8];
    }
}

// ---------------- grouped conv(h) + 1x1(conv|residual) + center/scale/split (512 thr) ----
__global__ __launch_bounds__(512) void conv2_m(
        const unsigned short* __restrict__ hh, const unsigned short* __restrict__ hl,
        const unsigned short* __restrict__ xbh, const unsigned short* __restrict__ xbl,
        const unsigned short* __restrict__ wth, const unsigned short* __restrict__ wtl,
        const float* __restrict__ bias2,
        const unsigned short* __restrict__ wph, const unsigned short* __restrict__ wpl,
        const float* __restrict__ biasq, float scaleOut,
        unsigned short* __restrict__ Qh, unsigned short* __restrict__ Ql) {
    __shared__ unsigned short rs[8*4608];   // per-wave [32px][72] hi+lo ; aliased f32 [256][68] later
    __shared__ float red2[512];
    __shared__ float meanl[64];
    int blk = blockIdx.x;
    int y = blk & 255, b = blk >> 8;
    int t = threadIdx.x;
    int w = t >> 6, l = t & 63;
    int lr = l & 15, lg = l >> 4;

    // ---- phase A: grouped conv on h ----
    f32x4 acc[2][4];
    #pragma unroll
    for (int g = 0; g < 4; ++g) {
        float bb = bias2[g*16 + lr];
        #pragma unroll
        for (int mt = 0; mt < 2; ++mt) acc[mt][g] = (f32x4){bb,bb,bb,bb};
    }
    size_t lanebase = ((size_t)(b*258 + y)*258 + 32*w + lr)*64 + (lg & 1)*8;
    int koff[5];
    #pragma unroll
    for (int ks = 0; ks < 5; ++ks) {
        int tap = 2*ks + (lg >> 1);
        if (tap > 8) tap = 8;
        koff[ks] = ((tap/3)*258 + (tap%3))*64;
    }
    #pragma unroll
    for (int ks = 0; ks < 5; ++ks) {
        #pragma unroll
        for (int g = 0; g < 4; ++g) {
            short8 bh = *(const short8*)(wth + (g*16+lr)*160 + ks*32 + lg*8);
            short8 bl = *(const short8*)(wtl + (g*16+lr)*160 + ks*32 + lg*8);
            #pragma unroll
            for (int mt = 0; mt < 2; ++mt) {
                size_t off = lanebase + koff[ks] + mt*1024 + g*16;
                short8 ah = *(const short8*)(hh + off);
                short8 al = *(const short8*)(hl + off);
                acc[mt][g] = __builtin_amdgcn_mfma_f32_16x16x32_bf16(ah, bh, acc[mt][g], 0,0,0);
                acc[mt][g] = __builtin_amdgcn_mfma_f32_16x16x32_bf16(ah, bl, acc[mt][g], 0,0,0);
                acc[mt][g] = __builtin_amdgcn_mfma_f32_16x16x32_bf16(al, bh, acc[mt][g], 0,0,0);
            }
        }
    }
    unsigned short* rsw = rs + w*4608;      // [32][72] hi + [32][72] lo
    #pragma unroll
    for (int mt = 0; mt < 2; ++mt)
        #pragma unroll
        for (int g = 0; g < 4; ++g)
            #pragma unroll
            for (int r = 0; r < 4; ++r) {
                float v = acc[mt][g][r];
                int pxl = mt*16 + lg*4 + r;
                int oc = g*16 + lr;
                unsigned short hv = f2bf(v);
                rsw[pxl*72 + oc] = hv;
                rsw[2304 + pxl*72 + oc] = f2bf(v - bf2f(hv));
            }
    // ---- phase B: 1x1 GEMM K=128 ----
    f32x4 acc2[2][4];
    #pragma unroll
    for (int nt = 0; nt < 4; ++nt) {
        float bb = biasq[nt*16 + lr];
        #pragma unroll
        for (int mt = 0; mt < 2; ++mt) acc2[mt][nt] = (f32x4){bb,bb,bb,bb};
    }
    size_t cbase = ((size_t)(b*258 + y+1)*258 + 32*w + lr + 1)*64 + lg*8;
    #pragma unroll
    for (int ks = 0; ks < 4; ++ks) {
        short8 Ah[2], Al[2];
        #pragma unroll
        for (int mt = 0; mt < 2; ++mt) {
            if (ks < 2) {
                Ah[mt] = *(short8*)&rsw[(mt*16+lr)*72 + ks*32 + lg*8];
                Al[mt] = *(short8*)&rsw[2304 + (mt*16+lr)*72 + ks*32 + lg*8];
            } else {
                size_t off = cbase + (size_t)mt*1024 + (ks-2)*32;
                Ah[mt] = *(const short8*)(xbh + off);
                Al[mt] = *(const short8*)(xbl + off);
            }
        }
        #pragma unroll
        for (int nt = 0; nt < 4; ++nt) {
            short8 Bh = *(const short8*)(wph + (nt*16+lr)*128 + ks*32 + lg*8);
            short8 Bl = *(const short8*)(wpl + (nt*16+lr)*128 + ks*32 + lg*8);
            #pragma unroll
            for (int mt = 0; mt < 2; ++mt) {
                acc2[mt][nt] = __builtin_amdgcn_mfma_f32_16x16x32_bf16(Ah[mt], Bh, acc2[mt][nt], 0,0,0);
                acc2[mt][nt] = __builtin_amdgcn_mfma_f32_16x16x32_bf16(Ah[mt], Bl, acc2[mt][nt], 0,0,0);
                acc2[mt][nt] = __builtin_amdgcn_mfma_f32_16x16x32_bf16(Al[mt], Bh, acc2[mt][nt], 0,0,0);
            }
        }
    }
    __syncthreads();
    // ---- phase C: mean-center over width, scale, split ----
    float* qs = (float*)rs;   // [256][68]
    #pragma unroll
    for (int mt = 0; mt < 2; ++mt)
        #pragma unroll
        for (int nt = 0; nt < 4; ++nt)
            #pragma unroll
            for (int r = 0; r < 4; ++r)
                qs[(32*w + mt*16 + lg*4 + r)*68 + nt*16 + lr] = acc2[mt][nt][r];
    __syncthreads();
    {
        int c = t & 63, seg = t >> 6;
        float s = 0.f;
        for (int i = 0; i < 32; ++i) s += qs[(seg*32 + i)*68 + c];
        red2[t] = s;
    }
    __syncthreads();
    if (t < 64) {
        float s = 0.f;
        #pragma unroll
        for (int seg = 0; seg < 8; ++seg) s += red2[seg*64 + t];
        meanl[t] = s * (1.f/256.f);
    }
    __syncthreads();
    int n = b*256 + y;
    int px = t >> 1, half = (t & 1) * 32;
    size_t obase = ((size_t)n*256 + px)*64;
    #pragma unroll
    for (int cc = 0; cc < 2; ++cc) {
        int cb = half + cc*16;
        short8 h0, h1, l0, l1;
        #pragma unroll
        for (int j = 0; j < 8; ++j) {
            int c = cb + j;
            float f = (qs[px*68 + c] - meanl[c]) * scaleOut;
            unsigned short hv = f2bf(f);
            h0[j] = (short)hv; l0[j] = (short)f2bf(f - bf2f(hv));
        }
        #pragma unroll
        for (int j = 0; j < 8; ++j) {
            int c = cb + 8 + j;
            float f = (qs[px*68 + c] - meanl[c]) * scaleOut;
            unsigned short hv = f2bf(f);
            h1[j] = (short)hv; l1[j] = (short)f2bf(f - bf2f(hv));
        }
        *(short8*)(Qh + obase + cb)     = h0;
        *(short8*)(Qh + obase + cb + 8) = h1;
        *(short8*)(Ql + obase + cb)     = l0;
        *(short8*)(Ql + obase + cb + 8) = l1;
    }
}

// ---------------- attention stats (512 thr, 8 waves x 32 rows) ----------------
__global__ __launch_bounds__(512) void s1_stats(
        const unsigned short* __restrict__ Qhi, const unsigned short* __restrict__ Qlo,
        const unsigned short* __restrict__ Khi, const unsigned short* __restrict__ Klo,
        float* __restrict__ rmax, float* __restrict__ rinv,
        float* __restrict__ cmax, float* __restrict__ cinv) {
    __shared__ float colred[8][256][2];
    int n = blockIdx.x;
    int t = threadIdx.x;
    int w = t >> 6, l = t & 63;
    int lr = l & 15, lg = l >> 4;
    const size_t qb = (size_t)n * 16384;

    short8 qh[2][2], ql[2][2];
    #pragma unroll
    for (int rf = 0; rf < 2; ++rf)
        #pragma unroll
        for (int ks = 0; ks < 2; ++ks) {
            size_t a = qb + (size_t)(w*32 + rf*16 + lr)*64 + ks*32 + lg*8;
            qh[rf][ks] = *reinterpret_cast<const short8*>(Qhi + a);
            ql[rf][ks] = *reinterpret_cast<const short8*>(Qlo + a);
        }
    float mrow[2][4], srow[2][4];
    #pragma unroll
    for (int rf = 0; rf < 2; ++rf)
        #pragma unroll
        for (int r = 0; r < 4; ++r) { mrow[rf][r] = -3.0e38f; srow[rf][r] = 0.f; }

    for (int jt = 0; jt < 8; ++jt) {
        short8 kh[2][2], kl[2][2];
        #pragma unroll
        for (int cf = 0; cf < 2; ++cf)
            #pragma unroll
            for (int ks = 0; ks < 2; ++ks) {
                size_t a = qb + (size_t)(jt*32 + cf*16 + lr)*64 + ks*32 + lg*8;
                kh[cf][ks] = *reinterpret_cast<const short8*>(Khi + a);
                kl[cf][ks] = *reinterpret_cast<const short8*>(Klo + a);
            }
        f32x4 acc[2][2];
        #pragma unroll
        for (int rf = 0; rf < 2; ++rf)
            #pragma unroll
            for (int cf = 0; cf < 2; ++cf) acc[rf][cf] = (f32x4){0.f,0.f,0.f,0.f};
        #pragma unroll
        for (int ks = 0; ks < 2; ++ks)
            #pragma unroll
            for (int rf = 0; rf < 2; ++rf)
                #pragma unroll
                for (int cf = 0; cf < 2; ++cf) {
                    acc[rf][cf] = __builtin_amdgcn_mfma_f32_16x16x32_bf16(qh[rf][ks], kh[cf][ks], acc[rf][cf], 0,0,0);
                    acc[rf][cf] = __builtin_amdgcn_mfma_f32_16x16x32_bf16(qh[rf][ks], kl[cf][ks], acc[rf][cf], 0,0,0);
                    acc[rf][cf] = __builtin_amdgcn_mfma_f32_16x16x32_bf16(ql[rf][ks], kh[cf][ks], acc[rf][cf], 0,0,0);
                }
        #pragma unroll
        for (int rf = 0; rf < 2; ++rf)
            #pragma unroll
            for (int r = 0; r < 4; ++r) {
                float e0 = acc[rf][0][r], e1 = acc[rf][1][r];
                float m2 = fmaxf(mrow[rf][r], fmaxf(e0, e1));
                srow[rf][r] = srow[rf][r]*exp2f(mrow[rf][r]-m2) + exp2f(e0-m2) + exp2f(e1-m2);
                mrow[rf][r] = m2;
            }
        #pragma unroll
        for (int cf = 0; cf < 2; ++cf) {
            float m = acc[0][cf][0];
            #pragma unroll
            for (int rf = 0; rf < 2; ++rf)
                #pragma unroll
                for (int r = 0; r < 4; ++r) m = fmaxf(m, acc[rf][cf][r]);
            float s = 0.f;
            #pragma unroll
            for (int rf = 0; rf < 2; ++rf)
                #pragma unroll
                for (int r = 0; r < 4; ++r) s += exp2f(acc[rf][cf][r] - m);
            #pragma unroll
            for (int mask = 16; mask <= 32; mask <<= 1) {
                float om = __shfl_xor(m, mask);
                float os = __shfl_xor(s, mask);
                float m2 = fmaxf(m, om);
                s = s*exp2f(m-m2) + os*exp2f(om-m2);
                m = m2;
            }
            if (lg == 0) {
                int j = jt*32 + cf*16 + lr;
                colred[w][j][0] = m;
                colred[w][j][1] = s;
            }
        }
    }
    #pragma unroll
    for (int rf = 0; rf < 2; ++rf)
        #pragma unroll
        for (int r = 0; r < 4; ++r) {
            float m = mrow[rf][r], s = srow[rf][r];
            #pragma unroll
            for (int mask = 1; mask <= 8; mask <<= 1) {
                float om = __shfl_xor(m, mask);
                float os = __shfl_xor(s, mask);
                float m2 = fmaxf(m, om);
                s = s*exp2f(m-m2) + os*exp2f(om-m2);
                m = m2;
            }
            if (lr == 0) {
                int row = w*32 + rf*16 + lg*4 + r;
                rmax[n*256 + row] = m;
                rinv[n*256 + row] = 1.f / s;
            }
        }
    __syncthreads();
    if (t < 256) {
        int j = t;
        float m = colred[0][j][0], s = colred[0][j][1];
        #pragma unroll
        for (int w2_ = 1; w2_ < 8; ++w2_) {
            float om = colred[w2_][j][0], os = colred[w2_][j][1];
            float m2 = fmaxf(m, om);
            s = s*exp2f(m-m2) + os*exp2f(om-m2);
            m = m2;
        }
        cmax[n*256 + j] = m;
        cinv[n*256 + j] = 1.f / s;
    }
}

// ---------------- apply (512 thr).  pa unnormalized; rin folded into band + PV epilogue ----
__global__ __launch_bounds__(512) void s23_apply(
        const unsigned short* __restrict__ Ahi, const unsigned short* __restrict__ Alo,
        const unsigned short* __restrict__ Bhi, const unsigned short* __restrict__ Blo,
        const float* __restrict__ rowmax, const float* __restrict__ rowinv,
        const float* __restrict__ colmax, const float* __restrict__ colinv,
        const unsigned short* __restrict__ Xpv16, const float* __restrict__ Xblend,
        float* __restrict__ outp) {
    __shared__ unsigned short pa[256][40];
    __shared__ unsigned short pb[256][40];
    __shared__ float vred[8][256];
    __shared__ float cmax_l[256], cinv_l[256];
    __shared__ float vfin[256];
    int n = blockIdx.x;
    int y = n & 255, b = n >> 8;
    int t = threadIdx.x;
    int w = t >> 6, l = t & 63;
    int lr = l & 15, lg = l >> 4;
    const size_t qb = (size_t)n * 16384;

    if (t < 256) {
        cmax_l[t] = colmax[n*256 + t];
        cinv_l[t] = colinv[n*256 + t];
    }
    for (int q = t; q < 2048; q += 512) ((float*)vred)[q] = 0.f;

    float rmx[2][4], rin[2][4];
    #pragma unroll
    for (int rf = 0; rf < 2; ++rf)
        #pragma unroll
        for (int r = 0; r < 4; ++r) {
            int row = w*32 + rf*16 + lg*4 + r;
            rmx[rf][r] = rowmax[n*256 + row];
            rin[rf][r] = rowinv[n*256 + row];
        }
    short8 ah[2][2], al[2][2];
    #pragma unroll
    for (int rf = 0; rf < 2; ++rf)
        #pragma unroll
        for (int ks = 0; ks < 2; ++ks) {
            size_t a = qb + (size_t)(w*32 + rf*16 + lr)*64 + ks*32 + lg*8;
            ah[rf][ks] = *reinterpret_cast<const short8*>(Ahi + a);
            al[rf][ks] = *reinterpret_cast<const short8*>(Alo + a);
        }
    f32x4 pv[2][4];
    #pragma unroll
    for (int rf = 0; rf < 2; ++rf)
        #pragma unroll
        for (int cf = 0; cf < 4; ++cf) pv[rf][cf] = (f32x4){0.f,0.f,0.f,0.f};
    float vacc[4];
    #pragma unroll
    for (int s = 0; s < 4; ++s) vacc[s] = 0.f;

    __syncthreads();

    for (int jt = 0; jt < 8; ++jt) {
        short8 bh[2][2], bl[2][2];
        #pragma unroll
        for (int cf = 0; cf < 2; ++cf)
            #pragma unroll
            for (int ks = 0; ks < 2; ++ks) {
                size_t a = qb + (size_t)(jt*32 + cf*16 + lr)*64 + ks*32 + lg*8;
                bh[cf][ks] = *reinterpret_cast<const short8*>(Bhi + a);
                bl[cf][ks] = *reinterpret_cast<const short8*>(Blo + a);
            }
        f32x4 acc[2][2];
        #pragma unroll
        for (int rf = 0; rf < 2; ++rf)
            #pragma unroll
            for (int cf = 0; cf < 2; ++cf) acc[rf][cf] = (f32x4){0.f,0.f,0.f,0.f};
        #pragma unroll
        for (int ks = 0; ks < 2; ++ks)
            #pragma unroll
            for (int rf = 0; rf < 2; ++rf)
                #pragma unroll
                for (int cf = 0; cf < 2; ++cf) {
                    acc[rf][cf] = __builtin_amdgcn_mfma_f32_16x16x32_bf16(ah[rf][ks], bh[cf][ks], acc[rf][cf], 0,0,0);
                    acc[rf][cf] = __builtin_amdgcn_mfma_f32_16x16x32_bf16(ah[rf][ks], bl[cf][ks], acc[rf][cf], 0,0,0);
                    acc[rf][cf] = __builtin_amdgcn_mfma_f32_16x16x32_bf16(al[rf][ks], bh[cf][ks], acc[rf][cf], 0,0,0);
                }
        #pragma unroll
        for (int rf = 0; rf < 2; ++rf)
            #pragma unroll
            for (int cf = 0; cf < 2; ++cf) {
                int col = cf*16 + lr;
                float cm = cmax_l[jt*32 + col];
                float ci = cinv_l[jt*32 + col];
                #pragma unroll
                for (int r = 0; r < 4; ++r) {
                    float e = acc[rf][cf][r];
                    int row = w*32 + rf*16 + lg*4 + r;
                    pa[row][col] = f2bf(exp2f(e - rmx[rf][r]));          // unnormalized
                    pb[row][col] = f2bf(exp2f(e - cm) * ci);
                }
            }
        __syncthreads();
        // banded W = a~ @ b^T ; scale rows by rin before extraction
        #pragma unroll
        for (int Tl = 0; Tl < 2; ++Tl) {
            int T = w*2 + Tl;
            short8 afr = *reinterpret_cast<short8*>(&pa[T*16 + lr][lg*8]);
            #pragma unroll
            for (int dT = -1; dT <= 1; ++dT) {
                int Tp = T + dT;
                if (Tp < 0 || Tp > 15) continue;
                short8 bfr = *reinterpret_cast<short8*>(&pb[Tp*16 + lr][lg*8]);
                f32x4 wacc = (f32x4){0.f,0.f,0.f,0.f};
                wacc = __builtin_amdgcn_mfma_f32_16x16x32_bf16(afr, bfr, wacc, 0,0,0);
                #pragma unroll
                for (int r = 0; r < 4; ++r) {
                    int diff = lg*4 + r - lr - 16*dT;
                    if (diff >= -2 && diff <= 2) vacc[Tl + dT + 1] += wacc[r] * rin[Tl][r];
                }
            }
        }
        // PV: OL~ += a~ @ Xpv (bf16 CHW direct loads)
        #pragma unroll
        for (int cf4 = 0; cf4 < 4; ++cf4) {
            short8 xf = *(const short8*)(Xpv16 + (((size_t)(b*64 + cf4*16 + lr))*256 + y)*256 + jt*32 + lg*8);
            #pragma unroll
            for (int rf = 0; rf < 2; ++rf) {
                short8 paf = *reinterpret_cast<short8*>(&pa[w*32 + rf*16 + lr][lg*8]);
                pv[rf][cf4] = __builtin_amdgcn_mfma_f32_16x16x32_bf16(paf, xf, pv[rf][cf4], 0,0,0);
            }
        }
        __syncthreads();
    }
    #pragma unroll
    for (int s = 0; s < 4; ++s) {
        float v = vacc[s];
        v += __shfl_xor(v, 16);
        v += __shfl_xor(v, 32);
        if (lg == 0) {
            int i = (w*2 - 1 + s)*16 + lr;
            if (i >= 0 && i < 256) vred[w][i] = v;
        }
    }
    __syncthreads();
    if (t < 256) {
        float s = 0.f;
        #pragma unroll
        for (int ww = 0; ww < 8; ++ww) s += vred[ww][t];
        vfin[t] = tanhf(5.f * s);
    }
    __syncthreads();
    const float* xbb = Xblend + (size_t)b*CC*HWp + (size_t)y*WW;
    float* ob = outp + (size_t)b*CC*HWp + (size_t)y*WW;
    #pragma unroll
    for (int rf = 0; rf < 2; ++rf)
        #pragma unroll
        for (int r = 0; r < 4; ++r) {
            int row = w*32 + rf*16 + lg*4 + r;
            float vt = vfin[row];
            float ri = rin[rf][r];
            #pragma unroll
            for (int cf4 = 0; cf4 < 4; ++cf4) {
                int c = cf4*16 + lr;
                size_t ga = (size_t)c*HWp + row;
                float xv = xbb[ga];
                ob[ga] = xv + vt * (pv[rf][cf4][r]*ri - xv);
            }
        }
}

extern "C" void kernel_launch(void* const* d_in, const int* in_sizes, int n_in,
                              void* d_out, int out_size, void* d_ws, size_t ws_size,
                              hipStream_t stream) {
    const float* x_left  = (const float*)d_in[0];
    const float* x_right = (const float*)d_in[1];
    const float* bn_g = (const float*)d_in[4];
    const float* bn_b = (const float*)d_in[5];
    const float* bn_m = (const float*)d_in[6];
    const float* bn_v = (const float*)d_in[7];
    const float* w1  = (const float*)d_in[8];
    const float* b1  = (const float*)d_in[9];
    const float* w2  = (const float*)d_in[10];
    const float* b2  = (const float*)d_in[11];
    const float* bqw = (const float*)d_in[12];
    const float* bqb = (const float*)d_in[13];
    const float* bsw = (const float*)d_in[14];
    const float* bsb = (const float*)d_in[15];

    char* base = (char*)d_ws;
    float* bnss = (float*)(base + OFS_BNSS);
    unsigned short* w1h = (unsigned short*)(base + OFS_W1H);
    unsigned short* w1l = (unsigned short*)(base + OFS_W1L);
    unsigned short* w2h = (unsigned short*)(base + OFS_W2H);
    unsigned short* w2l = (unsigned short*)(base + OFS_W2L);
    unsigned short* wqh = (unsigned short*)(base + OFS_WQH);
    unsigned short* wql = (unsigned short*)(base + OFS_WQL);
    unsigned short* wsh = (unsigned short*)(base + OFS_WSH);
    unsigned short* wsl = (unsigned short*)(base + OFS_WSL);
    float* rmaxp = (float*)(base + OFS_RMAX);
    float* rinvp = (float*)(base + OFS_RINV);
    float* cmaxp = (float*)(base + OFS_CMAX);
    float* cinvp = (float*)(base + OFS_CINV);
    unsigned short* xbh = (unsigned short*)(base + OFS_XBNH);
    unsigned short* xbl = (unsigned short*)(base + OFS_XBNL);
    unsigned short* hh  = (unsigned short*)(base + OFS_HH);
    unsigned short* hl  = (unsigned short*)(base + OFS_HL);
    unsigned short* Qh  = (unsigned short*)(base + OFS_QH);
    unsigned short* Ql  = (unsigned short*)(base + OFS_QL);
    unsigned short* Kh  = (unsigned short*)(base + OFS_KH);
    unsigned short* Kl  = (unsigned short*)(base + OFS_KL);
    unsigned short* xlb = (unsigned short*)(base + OFS_XLB);
    unsigned short* xrb = (unsigned short*)(base + OFS_XRB);

    float* outl = (float*)d_out;
    float* outr = outl + (size_t)2*CC*HWp;

    hipLaunchKernelGGL(wprep, dim3(1), dim3(256), 0, stream,
                       bn_g, bn_b, bn_m, bn_v, w1, w2, bqw, bsw,
                       bnss, w1h, w1l, w2h, w2l, wqh, wql, wsh, wsl);
    hipLaunchKernelGGL(zhalo, dim3(257), dim3(256), 0, stream, (unsigned short*)(base + OFS_XBNH));
    // left -> Q
    hipLaunchKernelGGL(prep_k,  dim3(512), dim3(512), 0, stream, x_left, bnss, xbh, xbl, xlb);
    hipLaunchKernelGGL(conv1_m, dim3(512), dim3(512), 0, stream, xbh, xbl, w1h, w1l, b1, hh, hl);
    hipLaunchKernelGGL(conv2_m, dim3(512), dim3(512), 0, stream, hh, hl, xbh, xbl,
                       w2h, w2l, b2, wqh, wql, bqb, LOG2E, Qh, Ql);
    // right -> K
    hipLaunchKernelGGL(prep_k,  dim3(512), dim3(512), 0, stream, x_right, bnss, xbh, xbl, xrb);
    hipLaunchKernelGGL(conv1_m, dim3(512), dim3(512), 0, stream, xbh, xbl, w1h, w1l, b1, hh, hl);
    hipLaunchKernelGGL(conv2_m, dim3(512), dim3(512), 0, stream, hh, hl, xbh, xbl,
                       w2h, w2l, b2, wsh, wsl, bsb, 1.0f, Kh, Kl);
    // attention
    hipLaunchKernelGGL(s1_stats, dim3(512), dim3(512), 0, stream, Qh, Ql, Kh, Kl, rmaxp, rinvp, cmaxp, cinvp);
    hipLaunchKernelGGL(s23_apply, dim3(512), dim3(512), 0, stream,
                       Qh, Ql, Kh, Kl, rmaxp, rinvp, cmaxp, cinvp, xrb, x_left, outl);
    hipLaunchKernelGGL(s23_apply, dim3(512), dim3(512), 0, stream,
                       Kh, Kl, Qh, Ql, cmaxp, cinvp, rmaxp, rinvp, xlb, x_right, outr);
}